// Round 10
// baseline (1315.878 us; speedup 1.0000x reference)
//
#include <hip/hip_runtime.h>
#include <stdint.h>

typedef unsigned int u32;
typedef unsigned long long u64;
typedef int v4i __attribute__((ext_vector_type(4)));
typedef int v16i __attribute__((ext_vector_type(16)));

// ---------------------------------------------------------------------------
// Threefry-2x32, 20 rounds — bit-exact replica of JAX's threefry2x32 primitive.
// ---------------------------------------------------------------------------
__host__ __device__ __forceinline__ void tf2x32(u32 k0, u32 k1, u32 x0, u32 x1,
                                                u32& o0, u32& o1) {
  u32 k2 = k0 ^ k1 ^ 0x1BD11BDAu;
  x0 += k0; x1 += k1;
#define TFR(r) { x0 += x1; x1 = (x1 << (r)) | (x1 >> (32 - (r))); x1 ^= x0; }
  TFR(13) TFR(15) TFR(26) TFR(6)   x0 += k1; x1 += k2 + 1u;
  TFR(17) TFR(29) TFR(16) TFR(24)  x0 += k2; x1 += k0 + 2u;
  TFR(13) TFR(15) TFR(26) TFR(6)   x0 += k0; x1 += k1 + 3u;
  TFR(17) TFR(29) TFR(16) TFR(24)  x0 += k1; x1 += k2 + 4u;
  TFR(13) TFR(15) TFR(26) TFR(6)   x0 += k2; x1 += k0 + 5u;
#undef TFR
  o0 = x0; o1 = x1;
}

// stoch_act: p = clip((y+1)*0.5, 0, 1); u from partitionable random bits of
// flat index j: bits = o0 ^ o1 of TF(key, (0, j)). Returns true if out = -1.
__device__ __forceinline__ bool act_neg(float y, u32 k0, u32 k1, u32 j) {
  u32 o0, o1;
  tf2x32(k0, k1, 0u, j, o0, o1);
  u32 bits = o0 ^ o1;
  float u = __uint_as_float(0x3f800000u | (bits >> 9)) - 1.0f;
  float t = (y + 1.0f) * 0.5f;
  float p = fminf(fmaxf(t, 0.0f), 1.0f);
  return !(u < p);
}

// ---------------------------------------------------------------------------
// Conv weight pack directly into i8 MFMA B-fragment order.
// bf[((cot*W + kt)*9 + t)*256 + l*4 + i4], bytes b:
//   co = cot*32 + (l&31), ci = kt*32 + (l>>5)*16 + i4*4 + b, tap t.
// i8 = +1 if w>=0 else -1 (0x01 / 0xFF).
// ---------------------------------------------------------------------------
__global__ void k_pack_wfrag(const float* __restrict__ w, u32* __restrict__ bf,
                             int Cout, int Cin) {
  const int W = Cin >> 5;
  const int total = (Cout >> 5) * W * 9 * 256;
  int idx = blockIdx.x * blockDim.x + threadIdx.x;
  if (idx >= total) return;
  int i4 = idx & 3;
  int l = (idx >> 2) & 63;
  int t = (idx >> 8) % 9;
  int kt = (idx / 2304) % W;
  int cot = idx / (2304 * W);
  int co = cot * 32 + (l & 31);
  int ci0 = kt * 32 + (l >> 5) * 16 + i4 * 4;
  int kh = t / 3, kw = t % 3;
  u32 v = 0;
#pragma unroll
  for (int b = 0; b < 4; ++b) {
    float wf = w[((size_t)(co * Cin + ci0 + b) * 3 + kh) * 3 + kw];
    v |= (wf < 0.0f ? 0xFFu : 0x01u) << (8 * b);
  }
  bf[idx] = v;
}

// FC weight pack, transposed for coalesced lane=o loads: pwT[k4][o][j].
__global__ void k_pack_fcwT(const float* __restrict__ w, u32* __restrict__ pwT,
                            int O, int K) {
  int KW = K >> 5;
  int idx = blockIdx.x * blockDim.x + threadIdx.x;
  if (idx >= O * KW) return;
  int kw = idx % KW, o = idx / KW;
  u32 word = 0;
  for (int b = 0; b < 32; ++b)
    word |= (w[(size_t)o * K + kw * 32 + b] < 0.0f ? 1u : 0u) << b;
  int k4 = kw >> 2, j = kw & 3;
  pwT[((size_t)k4 * O + o) * 4 + j] = word;
}

// FC weight pack, row-major (fc3).
__global__ void k_pack_fcw(const float* __restrict__ w, u32* __restrict__ pw,
                           int O, int K) {
  int KW = K >> 5;
  int idx = blockIdx.x * blockDim.x + threadIdx.x;
  if (idx >= O * KW) return;
  int kw = idx % KW, o = idx / KW;
  u32 word = 0;
  for (int b = 0; b < 32; ++b)
    word |= (w[o * K + kw * 32 + b] < 0.0f ? 1u : 0u) << b;
  pw[idx] = word;
}

// ---------------------------------------------------------------------------
// conv1: fp32 x [64][3][32][32], binarized w1, +b1, stoch_act key0.
// Output PLANAR packed: a1[(n*4 + w)*1024 + y*32 + x]. One wave per (n,y,x).
// ---------------------------------------------------------------------------
__global__ __launch_bounds__(256) void k_conv1(
    const float* __restrict__ x, const float* __restrict__ w1,
    const float* __restrict__ b1, u32 k0, u32 k1, u32* __restrict__ out) {
  int wave = (blockIdx.x * 256 + threadIdx.x) >> 6;
  int lane = threadIdx.x & 63;
  int n = wave >> 10;
  int rem = wave & 1023;
  int y = rem >> 5, xx = rem & 31;

  float xv[27];
#pragma unroll
  for (int ci = 0; ci < 3; ++ci)
#pragma unroll
    for (int dy = -1; dy <= 1; ++dy)
#pragma unroll
      for (int dx = -1; dx <= 1; ++dx) {
        int gy = y + dy, gx = xx + dx;
        float v = 0.0f;
        if ((unsigned)gy < 32u && (unsigned)gx < 32u)
          v = x[((n * 3 + ci) * 32 + gy) * 32 + gx];
        xv[(ci * 3 + (dy + 1)) * 3 + (dx + 1)] = v;
      }

  u64 bm[2];
#pragma unroll
  for (int h = 0; h < 2; ++h) {
    int co = lane + h * 64;
    float acc = 0.0f;
#pragma unroll
    for (int kh = 0; kh < 3; ++kh)
#pragma unroll
      for (int kw = 0; kw < 3; ++kw)
#pragma unroll
        for (int ci = 0; ci < 3; ++ci) {
          int k = (ci * 3 + kh) * 3 + kw;
          float wv = w1[co * 27 + k];
          acc += (wv < 0.0f) ? -xv[k] : xv[k];
        }
    float yv = acc + b1[co];
    u32 j = ((u32)(n * 128 + co) << 10) | (u32)(y << 5) | (u32)xx;
    bm[h] = __ballot(act_neg(yv, k0, k1, j));
  }
  if (lane < 4) {
    u32 wsel = (lane & 1) ? (u32)(bm[lane >> 1] >> 32) : (u32)bm[lane >> 1];
    out[(u32)(n * 4 + lane) * 1024u + (u32)(y * 32 + xx)] = wsel;
  }
}

// ---------------------------------------------------------------------------
// Binary conv via i8 MFMA (layers 2..6), v8 — identical math/layout to the
// proven r9 kernel; ONE structural change: each wave owns TWO 32-cout chunks
// (cot0, cot0+1), so the 18 cached A-fragments feed 72 MFMAs per kt instead
// of 36 (ds_read:MFMA ratio 2:1 -> 1:1), and the z-grid (hence expand work,
// LDS traffic, barriers) halves.
// ---------------------------------------------------------------------------
template <int W>
__global__ __launch_bounds__(256, 2) void k_bconv8(
    const u32* __restrict__ in, const u32* __restrict__ bfrag,
    const float* __restrict__ bias, int Cout, u32 k0, u32 k1,
    u32* __restrict__ out) {
  const int tid = threadIdx.x;
  const int lane = tid & 63;
  const int wv = tid >> 6;
  const int n = blockIdx.x;
  const int y0 = blockIdx.y * 4;
  const int cot0 = (blockIdx.z * 4 + wv) * 2;
  const int WOUT = Cout >> 5;

  __shared__ u32 sl[8 * 6 * 36];

  v16i acc[2][4];
#pragma unroll
  for (int cc = 0; cc < 2; ++cc)
#pragma unroll
    for (int r = 0; r < 4; ++r)
#pragma unroll
      for (int e = 0; e < 16; ++e) acc[cc][r][e] = 0;

#pragma unroll 1
  for (int kt = 0; kt < W; ++kt) {
    // Expand ci-slice kt into LDS (i8 +-1, true 0 for OOB), transposed.
    for (int i = tid; i < 8 * 34 * 6; i += 256) {
      int ci4 = i & 7;
      int xc = (i >> 3) % 34;
      int r = i / 272;
      int gy = y0 - 1 + r, gx = xc - 1;
      u32 val = 0;
      if ((unsigned)gy < 32u && (unsigned)gx < 32u) {
        u32 word = in[(u32)(n * W + kt) * 1024u + (u32)(gy * 32 + gx)];
        u32 nib = (word >> (ci4 * 4)) & 0xFu;
        u32 spread = (nib * 0x00204081u) & 0x01010101u;
        val = (spread * 0xFEu) ^ 0x01010101u;
      }
      sl[(ci4 * 6 + r) * 36 + xc] = val;
    }
    __syncthreads();

    // Load the 18 distinct A-fragments into registers (conflict-free b32).
    u32 af[6][3][4];
    const int xb = lane & 31;
    const int cd0 = (lane >> 5) * 4;
#pragma unroll
    for (int sr = 0; sr < 6; ++sr)
#pragma unroll
      for (int dxx = 0; dxx < 3; ++dxx)
#pragma unroll
        for (int q = 0; q < 4; ++q)
          af[sr][dxx][q] = sl[((cd0 + q) * 6 + sr) * 36 + xb + dxx];

    const u32* bptr0 =
        bfrag + ((size_t)(cot0 * W + kt) * 9) * 256 + lane * 4;
    const u32* bptr1 =
        bfrag + ((size_t)((cot0 + 1) * W + kt) * 9) * 256 + lane * 4;
#pragma unroll
    for (int t = 0; t < 9; ++t) {
      v4i B0 = *(const v4i*)(bptr0 + t * 256);
      v4i B1 = *(const v4i*)(bptr1 + t * 256);
      const int dy = t / 3 - 1, dxx = t % 3;
#pragma unroll
      for (int r = 0; r < 4; ++r) {
        v4i A;
        A[0] = (int)af[r + dy + 1][dxx][0];
        A[1] = (int)af[r + dy + 1][dxx][1];
        A[2] = (int)af[r + dy + 1][dxx][2];
        A[3] = (int)af[r + dy + 1][dxx][3];
        acc[0][r] =
            __builtin_amdgcn_mfma_i32_32x32x32_i8(A, B0, acc[0][r], 0, 0, 0);
        acc[1][r] =
            __builtin_amdgcn_mfma_i32_32x32x32_i8(A, B1, acc[1][r], 0, 0, 0);
      }
    }
    __syncthreads();
  }

  // Epilogue: bias + stoch_act + ballot-pack into planar channel words.
#pragma unroll
  for (int cc = 0; cc < 2; ++cc) {
    const int cot = cot0 + cc;
    const int co = cot * 32 + (lane & 31);
    const float bo = bias[co];
    const u32 jb = (u32)(n * Cout + co) * 1024u;
#pragma unroll
    for (int r = 0; r < 4; ++r) {
      const int y = y0 + r;
#pragma unroll
      for (int reg = 0; reg < 16; ++reg) {
        const int mlo = (reg & 3) + 8 * (reg >> 2);
        const int m = mlo + 4 * (lane >> 5);
        float yv = (float)acc[cc][r][reg] + bo;
        bool neg = act_neg(yv, k0, k1, jb + (u32)(y * 32 + m));
        u64 b = __ballot(neg);
        if (lane == 0)
          out[(u32)(n * WOUT + cot) * 1024u + (u32)(y * 32 + mlo)] = (u32)b;
        else if (lane == 32)
          out[(u32)(n * WOUT + cot) * 1024u + (u32)(y * 32 + mlo + 4)] =
              (u32)(b >> 32);
      }
    }
  }
}

// ---------------------------------------------------------------------------
// Repack conv6 PLANAR output into FC1 row layout (x-packed).
// ---------------------------------------------------------------------------
__global__ void k_repack(const u32* __restrict__ a6, u32* __restrict__ f0) {
  int idx = blockIdx.x * blockDim.x + threadIdx.x;
  if (idx >= 4096 * 256) return;
  int w = idx & 255, r = idx >> 8;
  int n = r >> 6, chi = r & 63;
  int clo = w >> 5, yy = w & 31;
  int c = chi * 8 + clo;
  const u32* base = a6 + (u32)(n * 16 + (c >> 5)) * 1024u + (u32)(yy * 32);
  u32 sh = (u32)(c & 31);
  u32 word = 0;
#pragma unroll
  for (int xp = 0; xp < 32; ++xp)
    word |= ((base[xp] >> sh) & 1u) << xp;
  f0[idx] = word;
}

// ---------------------------------------------------------------------------
// Binary FC with transposed weights (proven round 4). Block 256 = 4 waves;
// 32 rows (LDS) x 64 outputs; wave handles 8 rows; lane = o.
// ---------------------------------------------------------------------------
template <int KW>
__global__ __launch_bounds__(256, 4) void k_fct(
    const u32* __restrict__ in, const u32* __restrict__ pwT,
    const float* __restrict__ bias, int O, u32 k0, u32 k1,
    u32* __restrict__ out) {
  const int tid = threadIdx.x, lane = tid & 63;
  const int wv = __builtin_amdgcn_readfirstlane(tid >> 6);
  const int rbase = blockIdx.x * 32;
  const int obase = blockIdx.y * 64;
  __shared__ __align__(16) u32 rows[32 * KW];
  for (int i = tid; i < 32 * KW; i += 256)
    rows[i] = in[(size_t)(rbase + i / KW) * KW + (i % KW)];
  __syncthreads();

  const int o = obase + lane;
  const int r0 = wv * 8;
  u32 acc[8];
#pragma unroll
  for (int rr = 0; rr < 8; ++rr) acc[rr] = 0;
  for (int k4 = 0; k4 < KW / 4; ++k4) {
    uint4 w4 = ((const uint4*)pwT)[(size_t)k4 * O + o];
#pragma unroll
    for (int rr = 0; rr < 8; ++rr) {
      uint4 av = *(const uint4*)&rows[(r0 + rr) * KW + k4 * 4];
      acc[rr] += __popc(av.x ^ w4.x) + __popc(av.y ^ w4.y) +
                 __popc(av.z ^ w4.z) + __popc(av.w ^ w4.w);
    }
  }
  const int OW = O >> 5;
  const float bo = bias[o];
#pragma unroll
  for (int rr = 0; rr < 8; ++rr) {
    int r = rbase + r0 + rr;
    float yv = (float)(KW * 32 - 2 * (int)acc[rr]) + bo;
    bool neg = act_neg(yv, k0, k1, (u32)r * (u32)O + (u32)o);
    u64 b = __ballot(neg);
    if (lane == 0) {
      out[(size_t)r * OW + (obase >> 5)] = (u32)b;
      out[(size_t)r * OW + (obase >> 5) + 1] = (u32)(b >> 32);
    }
  }
}

// FC3: [4096][32 words] x [10][32 words] -> fp32 +-1 output [4096][10].
__global__ __launch_bounds__(64) void k_fc3(
    const u32* __restrict__ in, const u32* __restrict__ pw,
    const float* __restrict__ bias, u32 k0, u32 k1,
    float* __restrict__ outp) {
  const int lane = threadIdx.x;
  const int r = blockIdx.x;
  __shared__ u32 row[32];
  if (lane < 32) row[lane] = in[(size_t)r * 32 + lane];
  __syncthreads();
  if (lane < 10) {
    int acc = 0;
#pragma unroll
    for (int k = 0; k < 32; ++k) acc += __popc(row[k] ^ pw[lane * 32 + k]);
    float yv = (float)(1024 - 2 * acc) + bias[lane];
    bool neg = act_neg(yv, k0, k1, (u32)r * 10u + (u32)lane);
    outp[(size_t)r * 10 + lane] = neg ? -1.0f : 1.0f;
  }
}

// ---------------------------------------------------------------------------
extern "C" void kernel_launch(void* const* d_in, const int* in_sizes, int n_in,
                              void* d_out, int out_size, void* d_ws,
                              size_t ws_size, hipStream_t stream) {
  const float* x   = (const float*)d_in[0];
  const float* w1  = (const float*)d_in[1];
  const float* b1  = (const float*)d_in[2];
  const float* w2  = (const float*)d_in[3];
  const float* b2  = (const float*)d_in[4];
  const float* w3  = (const float*)d_in[5];
  const float* b3  = (const float*)d_in[6];
  const float* w4  = (const float*)d_in[7];
  const float* b4  = (const float*)d_in[8];
  const float* w5  = (const float*)d_in[9];
  const float* b5  = (const float*)d_in[10];
  const float* w6  = (const float*)d_in[11];
  const float* b6  = (const float*)d_in[12];
  const float* fw1 = (const float*)d_in[13];
  const float* fb1 = (const float*)d_in[14];
  const float* fw2 = (const float*)d_in[15];
  const float* fb2 = (const float*)d_in[16];
  const float* fw3 = (const float*)d_in[17];
  const float* fb3 = (const float*)d_in[18];

  u32 K[9][2];
  for (int i = 0; i < 9; ++i) tf2x32(0u, 42u, 0u, (u32)i, K[i][0], K[i][1]);

  char* ws = (char*)d_ws;
  size_t off = 0;
  auto alloc = [&](size_t bytes) -> char* {
    char* p = ws + off;
    off += (bytes + 255) & ~(size_t)255;
    return p;
  };
  // i8 MFMA weight fragment buffers: Cout*9*Cin bytes each.
  u32* bf2  = (u32*)alloc(256u * 9 * 128);
  u32* bf3  = (u32*)alloc(256u * 9 * 256);
  u32* bf4  = (u32*)alloc(256u * 9 * 256);
  u32* bf5  = (u32*)alloc(512u * 9 * 256);
  u32* bf6  = (u32*)alloc(512u * 9 * 512);
  u32* pfw1 = (u32*)alloc(1024u * 256 * 4);
  u32* pfw2 = (u32*)alloc(1024u * 32 * 4);
  u32* pfw3 = (u32*)alloc(10u * 32 * 4);
  u32* a1   = (u32*)alloc(64u * 1024 * 4 * 4);
  u32* a2   = (u32*)alloc(64u * 1024 * 8 * 4);
  u32* a3   = (u32*)alloc(64u * 1024 * 8 * 4);
  u32* a4   = (u32*)alloc(64u * 1024 * 8 * 4);
  u32* a5   = (u32*)alloc(64u * 1024 * 16 * 4);
  u32* a6   = (u32*)alloc(64u * 1024 * 16 * 4);
  u32* f0   = (u32*)alloc(4096u * 256 * 4);
  u32* f1   = (u32*)alloc(4096u * 32 * 4);
  u32* f2   = (u32*)alloc(4096u * 32 * 4);
  (void)ws_size;  // ~27 MB of workspace

  int t;
  t = (256 / 32) * 4 * 9 * 256;
  k_pack_wfrag<<<(t + 255) / 256, 256, 0, stream>>>(w2, bf2, 256, 128);
  t = (256 / 32) * 8 * 9 * 256;
  k_pack_wfrag<<<(t + 255) / 256, 256, 0, stream>>>(w3, bf3, 256, 256);
  k_pack_wfrag<<<(t + 255) / 256, 256, 0, stream>>>(w4, bf4, 256, 256);
  t = (512 / 32) * 8 * 9 * 256;
  k_pack_wfrag<<<(t + 255) / 256, 256, 0, stream>>>(w5, bf5, 512, 256);
  t = (512 / 32) * 16 * 9 * 256;
  k_pack_wfrag<<<(t + 255) / 256, 256, 0, stream>>>(w6, bf6, 512, 512);
  t = 1024 * 256;
  k_pack_fcwT<<<(t + 255) / 256, 256, 0, stream>>>(fw1, pfw1, 1024, 8192);
  t = 1024 * 32;
  k_pack_fcwT<<<(t + 255) / 256, 256, 0, stream>>>(fw2, pfw2, 1024, 1024);
  t = 10 * 32;
  k_pack_fcw<<<(t + 255) / 256, 256, 0, stream>>>(fw3, pfw3, 10, 1024);

  k_conv1<<<16384, 256, 0, stream>>>(x, w1, b1, K[0][0], K[0][1], a1);
  k_bconv8<4><<<dim3(64, 8, 1), 256, 0, stream>>>(a1, bf2, b2, 256,
                                                  K[1][0], K[1][1], a2);
  k_bconv8<8><<<dim3(64, 8, 1), 256, 0, stream>>>(a2, bf3, b3, 256,
                                                  K[2][0], K[2][1], a3);
  k_bconv8<8><<<dim3(64, 8, 1), 256, 0, stream>>>(a3, bf4, b4, 256,
                                                  K[3][0], K[3][1], a4);
  k_bconv8<8><<<dim3(64, 8, 2), 256, 0, stream>>>(a4, bf5, b5, 512,
                                                  K[4][0], K[4][1], a5);
  k_bconv8<16><<<dim3(64, 8, 2), 256, 0, stream>>>(a5, bf6, b6, 512,
                                                   K[5][0], K[5][1], a6);
  k_repack<<<(4096 * 256 + 255) / 256, 256, 0, stream>>>(a6, f0);
  k_fct<256><<<dim3(128, 16), 256, 0, stream>>>(f0, pfw1, fb1, 1024,
                                                K[6][0], K[6][1], f1);
  k_fct<32><<<dim3(128, 16), 256, 0, stream>>>(f1, pfw2, fb2, 1024,
                                               K[7][0], K[7][1], f2);
  k_fc3<<<4096, 64, 0, stream>>>(f2, pfw3, fb3, K[8][0], K[8][1],
                                 (float*)d_out);
}

// Round 12
// 708.791 us; speedup vs baseline: 1.8565x; 1.8565x over previous
//
#include <hip/hip_runtime.h>
#include <stdint.h>

typedef unsigned int u32;
typedef unsigned long long u64;
typedef int v4i __attribute__((ext_vector_type(4)));
typedef int v16i __attribute__((ext_vector_type(16)));

// ---------------------------------------------------------------------------
// Threefry-2x32, 20 rounds — bit-exact replica of JAX's threefry2x32 primitive.
// ---------------------------------------------------------------------------
__host__ __device__ __forceinline__ void tf2x32(u32 k0, u32 k1, u32 x0, u32 x1,
                                                u32& o0, u32& o1) {
  u32 k2 = k0 ^ k1 ^ 0x1BD11BDAu;
  x0 += k0; x1 += k1;
#define TFR(r) { x0 += x1; x1 = (x1 << (r)) | (x1 >> (32 - (r))); x1 ^= x0; }
  TFR(13) TFR(15) TFR(26) TFR(6)   x0 += k1; x1 += k2 + 1u;
  TFR(17) TFR(29) TFR(16) TFR(24)  x0 += k2; x1 += k0 + 2u;
  TFR(13) TFR(15) TFR(26) TFR(6)   x0 += k0; x1 += k1 + 3u;
  TFR(17) TFR(29) TFR(16) TFR(24)  x0 += k1; x1 += k2 + 4u;
  TFR(13) TFR(15) TFR(26) TFR(6)   x0 += k2; x1 += k0 + 5u;
#undef TFR
  o0 = x0; o1 = x1;
}

// stoch_act: p = clip((y+1)*0.5, 0, 1); u from partitionable random bits of
// flat index j: bits = o0 ^ o1 of TF(key, (0, j)). Returns true if out = -1.
__device__ __forceinline__ bool act_neg(float y, u32 k0, u32 k1, u32 j) {
  u32 o0, o1;
  tf2x32(k0, k1, 0u, j, o0, o1);
  u32 bits = o0 ^ o1;
  float u = __uint_as_float(0x3f800000u | (bits >> 9)) - 1.0f;
  float t = (y + 1.0f) * 0.5f;
  float p = fminf(fmaxf(t, 0.0f), 1.0f);
  return !(u < p);
}

// ---------------------------------------------------------------------------
// Conv weight pack directly into i8 MFMA B-fragment order.
// bf[((cot*W + kt)*9 + t)*256 + l*4 + i4], bytes b:
//   co = cot*32 + (l&31), ci = kt*32 + (l>>5)*16 + i4*4 + b, tap t.
// i8 = +1 if w>=0 else -1 (0x01 / 0xFF).
// ---------------------------------------------------------------------------
__global__ void k_pack_wfrag(const float* __restrict__ w, u32* __restrict__ bf,
                             int Cout, int Cin) {
  const int W = Cin >> 5;
  const int total = (Cout >> 5) * W * 9 * 256;
  int idx = blockIdx.x * blockDim.x + threadIdx.x;
  if (idx >= total) return;
  int i4 = idx & 3;
  int l = (idx >> 2) & 63;
  int t = (idx >> 8) % 9;
  int kt = (idx / 2304) % W;
  int cot = idx / (2304 * W);
  int co = cot * 32 + (l & 31);
  int ci0 = kt * 32 + (l >> 5) * 16 + i4 * 4;
  int kh = t / 3, kw = t % 3;
  u32 v = 0;
#pragma unroll
  for (int b = 0; b < 4; ++b) {
    float wf = w[((size_t)(co * Cin + ci0 + b) * 3 + kh) * 3 + kw];
    v |= (wf < 0.0f ? 0xFFu : 0x01u) << (8 * b);
  }
  bf[idx] = v;
}

// FC weight pack, transposed for coalesced lane=o loads: pwT[k4][o][j].
__global__ void k_pack_fcwT(const float* __restrict__ w, u32* __restrict__ pwT,
                            int O, int K) {
  int KW = K >> 5;
  int idx = blockIdx.x * blockDim.x + threadIdx.x;
  if (idx >= O * KW) return;
  int kw = idx % KW, o = idx / KW;
  u32 word = 0;
  for (int b = 0; b < 32; ++b)
    word |= (w[(size_t)o * K + kw * 32 + b] < 0.0f ? 1u : 0u) << b;
  int k4 = kw >> 2, j = kw & 3;
  pwT[((size_t)k4 * O + o) * 4 + j] = word;
}

// FC weight pack, row-major (fc3).
__global__ void k_pack_fcw(const float* __restrict__ w, u32* __restrict__ pw,
                           int O, int K) {
  int KW = K >> 5;
  int idx = blockIdx.x * blockDim.x + threadIdx.x;
  if (idx >= O * KW) return;
  int kw = idx % KW, o = idx / KW;
  u32 word = 0;
  for (int b = 0; b < 32; ++b)
    word |= (w[o * K + kw * 32 + b] < 0.0f ? 1u : 0u) << b;
  pw[idx] = word;
}

// ---------------------------------------------------------------------------
// conv1: fp32 x [64][3][32][32], binarized w1, +b1, stoch_act key0.
// Output PLANAR packed: a1[(n*4 + w)*1024 + y*32 + x]. One wave per (n,y,x).
// ---------------------------------------------------------------------------
__global__ __launch_bounds__(256) void k_conv1(
    const float* __restrict__ x, const float* __restrict__ w1,
    const float* __restrict__ b1, u32 k0, u32 k1, u32* __restrict__ out) {
  int wave = (blockIdx.x * 256 + threadIdx.x) >> 6;
  int lane = threadIdx.x & 63;
  int n = wave >> 10;
  int rem = wave & 1023;
  int y = rem >> 5, xx = rem & 31;

  float xv[27];
#pragma unroll
  for (int ci = 0; ci < 3; ++ci)
#pragma unroll
    for (int dy = -1; dy <= 1; ++dy)
#pragma unroll
      for (int dx = -1; dx <= 1; ++dx) {
        int gy = y + dy, gx = xx + dx;
        float v = 0.0f;
        if ((unsigned)gy < 32u && (unsigned)gx < 32u)
          v = x[((n * 3 + ci) * 32 + gy) * 32 + gx];
        xv[(ci * 3 + (dy + 1)) * 3 + (dx + 1)] = v;
      }

  u64 bm[2];
#pragma unroll
  for (int h = 0; h < 2; ++h) {
    int co = lane + h * 64;
    float acc = 0.0f;
#pragma unroll
    for (int kh = 0; kh < 3; ++kh)
#pragma unroll
      for (int kw = 0; kw < 3; ++kw)
#pragma unroll
        for (int ci = 0; ci < 3; ++ci) {
          int k = (ci * 3 + kh) * 3 + kw;
          float wv = w1[co * 27 + k];
          acc += (wv < 0.0f) ? -xv[k] : xv[k];
        }
    float yv = acc + b1[co];
    u32 j = ((u32)(n * 128 + co) << 10) | (u32)(y << 5) | (u32)xx;
    bm[h] = __ballot(act_neg(yv, k0, k1, j));
  }
  if (lane < 4) {
    u32 wsel = (lane & 1) ? (u32)(bm[lane >> 1] >> 32) : (u32)bm[lane >> 1];
    out[(u32)(n * 4 + lane) * 1024u + (u32)(y * 32 + xx)] = wsel;
  }
}

// ---------------------------------------------------------------------------
// Binary conv via i8 MFMA (layers 2..6), v10 — r11's pipelined structure with
// the OOB fix: padding cells must hold i8 ZERO, not the expansion of word 0
// (which is +1 bytes). `ein ? val : 0` restores the r9-proven semantics.
// ---------------------------------------------------------------------------
template <int W>
__global__ __launch_bounds__(256) void k_bconv9(
    const u32* __restrict__ in, const u32* __restrict__ bfrag,
    const float* __restrict__ bias, int Cout, u32 k0, u32 k1,
    u32* __restrict__ out) {
  const int tid = threadIdx.x;
  const int lane = tid & 63;
  const int wv = tid >> 6;
  const int n = blockIdx.x;
  const int y0 = blockIdx.y * 4;
  const int cot = blockIdx.z * 4 + wv;
  const int WOUT = Cout >> 5;

  __shared__ u32 sl[2][8 * 6 * 36];

  // Expand-item geometry: item = (row r, x col xc); 204 active threads.
  const int er = tid / 34;
  const int exc = tid % 34;
  const bool eact = tid < 204;
  const int egy = y0 - 1 + er;
  const int egx = exc - 1;
  const bool ein =
      eact && ((unsigned)egy < 32u) && ((unsigned)egx < 32u);

  v16i acc[4];
#pragma unroll
  for (int r = 0; r < 4; ++r)
#pragma unroll
    for (int e = 0; e < 16; ++e) acc[r][e] = 0;

  // Prologue: stage slice 0 (OOB cells = true i8 zero).
  {
    u32 word = ein ? in[(u32)(n * W) * 1024u + (u32)(egy * 32 + egx)] : 0u;
    if (eact) {
      u32* base = &sl[0][er * 36 + exc];
#pragma unroll
      for (int cd = 0; cd < 8; ++cd) {
        u32 nib = (word >> (cd * 4)) & 0xFu;
        u32 spread = (nib * 0x00204081u) & 0x01010101u;
        u32 val = (spread * 0xFEu) ^ 0x01010101u;
        base[cd * 216] = ein ? val : 0u;
      }
    }
  }
  __syncthreads();

#pragma unroll 1
  for (int kt = 0; kt < W; ++kt) {
    const int cur = kt & 1;
    // Early-issue next slice's global load (hides under af reads + MFMA).
    u32 wn = 0;
    if (kt + 1 < W && ein)
      wn = in[(u32)(n * W + kt + 1) * 1024u + (u32)(egy * 32 + egx)];

    // Load the 18 distinct A-fragments (conflict-free b32 reads).
    v4i af[18];
    const int xb = lane & 31;
    const int cd0 = (lane >> 5) * 4;
    const u32* slc = sl[cur];
#pragma unroll
    for (int sr = 0; sr < 6; ++sr)
#pragma unroll
      for (int dxx = 0; dxx < 3; ++dxx)
#pragma unroll
        for (int q = 0; q < 4; ++q)
          af[sr * 3 + dxx][q] =
              (int)slc[((cd0 + q) * 6 + sr) * 36 + xb + dxx];

    const u32* bptr = bfrag + ((size_t)(cot * W + kt) * 9) * 256 + lane * 4;
#pragma unroll
    for (int t = 0; t < 9; ++t) {
      v4i B = *(const v4i*)(bptr + t * 256);
      const int dy = t / 3 - 1, dxx = t % 3;
#pragma unroll
      for (int r = 0; r < 4; ++r)
        acc[r] = __builtin_amdgcn_mfma_i32_32x32x32_i8(
            af[(r + dy + 1) * 3 + dxx], B, acc[r], 0, 0, 0);
    }

    // Expand-write next slice (OOB cells = true i8 zero).
    if (kt + 1 < W && eact) {
      u32* base = &sl[cur ^ 1][er * 36 + exc];
#pragma unroll
      for (int cd = 0; cd < 8; ++cd) {
        u32 nib = (wn >> (cd * 4)) & 0xFu;
        u32 spread = (nib * 0x00204081u) & 0x01010101u;
        u32 val = (spread * 0xFEu) ^ 0x01010101u;
        base[cd * 216] = ein ? val : 0u;
      }
    }
    __syncthreads();
  }

  // Epilogue: bias + stoch_act + ballot-pack into planar channel words.
  const int co = cot * 32 + (lane & 31);
  const float bo = bias[co];
  const u32 jb = (u32)(n * Cout + co) * 1024u;
#pragma unroll
  for (int r = 0; r < 4; ++r) {
    const int y = y0 + r;
#pragma unroll
    for (int reg = 0; reg < 16; ++reg) {
      const int mlo = (reg & 3) + 8 * (reg >> 2);
      const int m = mlo + 4 * (lane >> 5);
      float yv = (float)acc[r][reg] + bo;
      bool neg = act_neg(yv, k0, k1, jb + (u32)(y * 32 + m));
      u64 b = __ballot(neg);
      if (lane == 0)
        out[(u32)(n * WOUT + cot) * 1024u + (u32)(y * 32 + mlo)] = (u32)b;
      else if (lane == 32)
        out[(u32)(n * WOUT + cot) * 1024u + (u32)(y * 32 + mlo + 4)] =
            (u32)(b >> 32);
    }
  }
}

// ---------------------------------------------------------------------------
// Repack conv6 PLANAR output into FC1 row layout (x-packed).
// ---------------------------------------------------------------------------
__global__ void k_repack(const u32* __restrict__ a6, u32* __restrict__ f0) {
  int idx = blockIdx.x * blockDim.x + threadIdx.x;
  if (idx >= 4096 * 256) return;
  int w = idx & 255, r = idx >> 8;
  int n = r >> 6, chi = r & 63;
  int clo = w >> 5, yy = w & 31;
  int c = chi * 8 + clo;
  const u32* base = a6 + (u32)(n * 16 + (c >> 5)) * 1024u + (u32)(yy * 32);
  u32 sh = (u32)(c & 31);
  u32 word = 0;
#pragma unroll
  for (int xp = 0; xp < 32; ++xp)
    word |= ((base[xp] >> sh) & 1u) << xp;
  f0[idx] = word;
}

// ---------------------------------------------------------------------------
// Binary FC with transposed weights (proven round 4). Block 256 = 4 waves;
// 32 rows (LDS) x 64 outputs; wave handles 8 rows; lane = o.
// ---------------------------------------------------------------------------
template <int KW>
__global__ __launch_bounds__(256, 4) void k_fct(
    const u32* __restrict__ in, const u32* __restrict__ pwT,
    const float* __restrict__ bias, int O, u32 k0, u32 k1,
    u32* __restrict__ out) {
  const int tid = threadIdx.x, lane = tid & 63;
  const int wv = __builtin_amdgcn_readfirstlane(tid >> 6);
  const int rbase = blockIdx.x * 32;
  const int obase = blockIdx.y * 64;
  __shared__ __align__(16) u32 rows[32 * KW];
  for (int i = tid; i < 32 * KW; i += 256)
    rows[i] = in[(size_t)(rbase + i / KW) * KW + (i % KW)];
  __syncthreads();

  const int o = obase + lane;
  const int r0 = wv * 8;
  u32 acc[8];
#pragma unroll
  for (int rr = 0; rr < 8; ++rr) acc[rr] = 0;
  for (int k4 = 0; k4 < KW / 4; ++k4) {
    uint4 w4 = ((const uint4*)pwT)[(size_t)k4 * O + o];
#pragma unroll
    for (int rr = 0; rr < 8; ++rr) {
      uint4 av = *(const uint4*)&rows[(r0 + rr) * KW + k4 * 4];
      acc[rr] += __popc(av.x ^ w4.x) + __popc(av.y ^ w4.y) +
                 __popc(av.z ^ w4.z) + __popc(av.w ^ w4.w);
    }
  }
  const int OW = O >> 5;
  const float bo = bias[o];
#pragma unroll
  for (int rr = 0; rr < 8; ++rr) {
    int r = rbase + r0 + rr;
    float yv = (float)(KW * 32 - 2 * (int)acc[rr]) + bo;
    bool neg = act_neg(yv, k0, k1, (u32)r * (u32)O + (u32)o);
    u64 b = __ballot(neg);
    if (lane == 0) {
      out[(size_t)r * OW + (obase >> 5)] = (u32)b;
      out[(size_t)r * OW + (obase >> 5) + 1] = (u32)(b >> 32);
    }
  }
}

// FC3: [4096][32 words] x [10][32 words] -> fp32 +-1 output [4096][10].
__global__ __launch_bounds__(64) void k_fc3(
    const u32* __restrict__ in, const u32* __restrict__ pw,
    const float* __restrict__ bias, u32 k0, u32 k1,
    float* __restrict__ outp) {
  const int lane = threadIdx.x;
  const int r = blockIdx.x;
  __shared__ u32 row[32];
  if (lane < 32) row[lane] = in[(size_t)r * 32 + lane];
  __syncthreads();
  if (lane < 10) {
    int acc = 0;
#pragma unroll
    for (int k = 0; k < 32; ++k) acc += __popc(row[k] ^ pw[lane * 32 + k]);
    float yv = (float)(1024 - 2 * acc) + bias[lane];
    bool neg = act_neg(yv, k0, k1, (u32)r * 10u + (u32)lane);
    outp[(size_t)r * 10 + lane] = neg ? -1.0f : 1.0f;
  }
}

// ---------------------------------------------------------------------------
extern "C" void kernel_launch(void* const* d_in, const int* in_sizes, int n_in,
                              void* d_out, int out_size, void* d_ws,
                              size_t ws_size, hipStream_t stream) {
  const float* x   = (const float*)d_in[0];
  const float* w1  = (const float*)d_in[1];
  const float* b1  = (const float*)d_in[2];
  const float* w2  = (const float*)d_in[3];
  const float* b2  = (const float*)d_in[4];
  const float* w3  = (const float*)d_in[5];
  const float* b3  = (const float*)d_in[6];
  const float* w4  = (const float*)d_in[7];
  const float* b4  = (const float*)d_in[8];
  const float* w5  = (const float*)d_in[9];
  const float* b5  = (const float*)d_in[10];
  const float* w6  = (const float*)d_in[11];
  const float* b6  = (const float*)d_in[12];
  const float* fw1 = (const float*)d_in[13];
  const float* fb1 = (const float*)d_in[14];
  const float* fw2 = (const float*)d_in[15];
  const float* fb2 = (const float*)d_in[16];
  const float* fw3 = (const float*)d_in[17];
  const float* fb3 = (const float*)d_in[18];

  u32 K[9][2];
  for (int i = 0; i < 9; ++i) tf2x32(0u, 42u, 0u, (u32)i, K[i][0], K[i][1]);

  char* ws = (char*)d_ws;
  size_t off = 0;
  auto alloc = [&](size_t bytes) -> char* {
    char* p = ws + off;
    off += (bytes + 255) & ~(size_t)255;
    return p;
  };
  // i8 MFMA weight fragment buffers: Cout*9*Cin bytes each.
  u32* bf2  = (u32*)alloc(256u * 9 * 128);
  u32* bf3  = (u32*)alloc(256u * 9 * 256);
  u32* bf4  = (u32*)alloc(256u * 9 * 256);
  u32* bf5  = (u32*)alloc(512u * 9 * 256);
  u32* bf6  = (u32*)alloc(512u * 9 * 512);
  u32* pfw1 = (u32*)alloc(1024u * 256 * 4);
  u32* pfw2 = (u32*)alloc(1024u * 32 * 4);
  u32* pfw3 = (u32*)alloc(10u * 32 * 4);
  u32* a1   = (u32*)alloc(64u * 1024 * 4 * 4);
  u32* a2   = (u32*)alloc(64u * 1024 * 8 * 4);
  u32* a3   = (u32*)alloc(64u * 1024 * 8 * 4);
  u32* a4   = (u32*)alloc(64u * 1024 * 8 * 4);
  u32* a5   = (u32*)alloc(64u * 1024 * 16 * 4);
  u32* a6   = (u32*)alloc(64u * 1024 * 16 * 4);
  u32* f0   = (u32*)alloc(4096u * 256 * 4);
  u32* f1   = (u32*)alloc(4096u * 32 * 4);
  u32* f2   = (u32*)alloc(4096u * 32 * 4);
  (void)ws_size;  // ~27 MB of workspace

  int t;
  t = (256 / 32) * 4 * 9 * 256;
  k_pack_wfrag<<<(t + 255) / 256, 256, 0, stream>>>(w2, bf2, 256, 128);
  t = (256 / 32) * 8 * 9 * 256;
  k_pack_wfrag<<<(t + 255) / 256, 256, 0, stream>>>(w3, bf3, 256, 256);
  k_pack_wfrag<<<(t + 255) / 256, 256, 0, stream>>>(w4, bf4, 256, 256);
  t = (512 / 32) * 8 * 9 * 256;
  k_pack_wfrag<<<(t + 255) / 256, 256, 0, stream>>>(w5, bf5, 512, 256);
  t = (512 / 32) * 16 * 9 * 256;
  k_pack_wfrag<<<(t + 255) / 256, 256, 0, stream>>>(w6, bf6, 512, 512);
  t = 1024 * 256;
  k_pack_fcwT<<<(t + 255) / 256, 256, 0, stream>>>(fw1, pfw1, 1024, 8192);
  t = 1024 * 32;
  k_pack_fcwT<<<(t + 255) / 256, 256, 0, stream>>>(fw2, pfw2, 1024, 1024);
  t = 10 * 32;
  k_pack_fcw<<<(t + 255) / 256, 256, 0, stream>>>(fw3, pfw3, 10, 1024);

  k_conv1<<<16384, 256, 0, stream>>>(x, w1, b1, K[0][0], K[0][1], a1);
  k_bconv9<4><<<dim3(64, 8, 2), 256, 0, stream>>>(a1, bf2, b2, 256,
                                                  K[1][0], K[1][1], a2);
  k_bconv9<8><<<dim3(64, 8, 2), 256, 0, stream>>>(a2, bf3, b3, 256,
                                                  K[2][0], K[2][1], a3);
  k_bconv9<8><<<dim3(64, 8, 2), 256, 0, stream>>>(a3, bf4, b4, 256,
                                                  K[3][0], K[3][1], a4);
  k_bconv9<8><<<dim3(64, 8, 4), 256, 0, stream>>>(a4, bf5, b5, 512,
                                                  K[4][0], K[4][1], a5);
  k_bconv9<16><<<dim3(64, 8, 4), 256, 0, stream>>>(a5, bf6, b6, 512,
                                                   K[5][0], K[5][1], a6);
  k_repack<<<(4096 * 256 + 255) / 256, 256, 0, stream>>>(a6, f0);
  k_fct<256><<<dim3(128, 16), 256, 0, stream>>>(f0, pfw1, fb1, 1024,
                                                K[6][0], K[6][1], f1);
  k_fct<32><<<dim3(128, 16), 256, 0, stream>>>(f1, pfw2, fb2, 1024,
                                               K[7][0], K[7][1], f2);
  k_fc3<<<4096, 64, 0, stream>>>(f2, pfw3, fb3, K[8][0], K[8][1],
                                 (float*)d_out);
}

// Round 13
// 708.183 us; speedup vs baseline: 1.8581x; 1.0009x over previous
//
#include <hip/hip_runtime.h>
#include <stdint.h>

typedef unsigned int u32;
typedef unsigned long long u64;
typedef int v4i __attribute__((ext_vector_type(4)));
typedef int v16i __attribute__((ext_vector_type(16)));

// ---------------------------------------------------------------------------
// Threefry-2x32, 20 rounds — bit-exact replica of JAX's threefry2x32 primitive.
// Rotations via __builtin_rotateleft32 to guarantee v_alignbit_b32.
// ---------------------------------------------------------------------------
__host__ __device__ __forceinline__ void tf2x32(u32 k0, u32 k1, u32 x0, u32 x1,
                                                u32& o0, u32& o1) {
  u32 k2 = k0 ^ k1 ^ 0x1BD11BDAu;
  x0 += k0; x1 += k1;
#ifdef __HIP_DEVICE_COMPILE__
#define ROTL(v, r) __builtin_rotateleft32((v), (r))
#else
#define ROTL(v, r) (((v) << (r)) | ((v) >> (32 - (r))))
#endif
#define TFR(r) { x0 += x1; x1 = ROTL(x1, r); x1 ^= x0; }
  TFR(13) TFR(15) TFR(26) TFR(6)   x0 += k1; x1 += k2 + 1u;
  TFR(17) TFR(29) TFR(16) TFR(24)  x0 += k2; x1 += k0 + 2u;
  TFR(13) TFR(15) TFR(26) TFR(6)   x0 += k0; x1 += k1 + 3u;
  TFR(17) TFR(29) TFR(16) TFR(24)  x0 += k1; x1 += k2 + 4u;
  TFR(13) TFR(15) TFR(26) TFR(6)   x0 += k2; x1 += k0 + 5u;
#undef TFR
#undef ROTL
  o0 = x0; o1 = x1;
}

// stoch_act: reference computes u = bitcast(0x3f800000|(bits>>9)) - 1 and
// p = clip((y+1)*0.5, 0, 1), out = -1 iff !(u < p). Since u in [0,1), the
// clip is redundant and u < p  <=>  2u < y+1 with 2u = fma(uf, 2, -2)
// (exact: real result is representable). Bit-identical decision, fewer ops.
__device__ __forceinline__ bool act_neg(float y, u32 k0, u32 k1, u32 j) {
  u32 o0, o1;
  tf2x32(k0, k1, 0u, j, o0, o1);
  u32 bits = o0 ^ o1;
  float uf = __uint_as_float(0x3f800000u | (bits >> 9));
  float u2 = __builtin_fmaf(uf, 2.0f, -2.0f);
  float t1 = y + 1.0f;
  return !(u2 < t1);
}

// ---------------------------------------------------------------------------
// Conv weight pack directly into i8 MFMA B-fragment order.
// bf[((cot*W + kt)*9 + t)*256 + l*4 + i4], bytes b:
//   co = cot*32 + (l&31), ci = kt*32 + (l>>5)*16 + i4*4 + b, tap t.
// i8 = +1 if w>=0 else -1 (0x01 / 0xFF).
// ---------------------------------------------------------------------------
__global__ void k_pack_wfrag(const float* __restrict__ w, u32* __restrict__ bf,
                             int Cout, int Cin) {
  const int W = Cin >> 5;
  const int total = (Cout >> 5) * W * 9 * 256;
  int idx = blockIdx.x * blockDim.x + threadIdx.x;
  if (idx >= total) return;
  int i4 = idx & 3;
  int l = (idx >> 2) & 63;
  int t = (idx >> 8) % 9;
  int kt = (idx / 2304) % W;
  int cot = idx / (2304 * W);
  int co = cot * 32 + (l & 31);
  int ci0 = kt * 32 + (l >> 5) * 16 + i4 * 4;
  int kh = t / 3, kw = t % 3;
  u32 v = 0;
#pragma unroll
  for (int b = 0; b < 4; ++b) {
    float wf = w[((size_t)(co * Cin + ci0 + b) * 3 + kh) * 3 + kw];
    v |= (wf < 0.0f ? 0xFFu : 0x01u) << (8 * b);
  }
  bf[idx] = v;
}

// FC weight pack, transposed for coalesced lane=o loads: pwT[k4][o][j].
// float4 reads (rows are contiguous).
__global__ void k_pack_fcwT(const float* __restrict__ w, u32* __restrict__ pwT,
                            int O, int K) {
  int KW = K >> 5;
  int idx = blockIdx.x * blockDim.x + threadIdx.x;
  if (idx >= O * KW) return;
  int kw = idx % KW, o = idx / KW;
  const float4* src = (const float4*)(w + (size_t)o * K + kw * 32);
  u32 word = 0;
#pragma unroll
  for (int b4 = 0; b4 < 8; ++b4) {
    float4 f = src[b4];
    word |= (f.x < 0.0f ? 1u : 0u) << (b4 * 4 + 0);
    word |= (f.y < 0.0f ? 1u : 0u) << (b4 * 4 + 1);
    word |= (f.z < 0.0f ? 1u : 0u) << (b4 * 4 + 2);
    word |= (f.w < 0.0f ? 1u : 0u) << (b4 * 4 + 3);
  }
  int k4 = kw >> 2, j = kw & 3;
  pwT[((size_t)k4 * O + o) * 4 + j] = word;
}

// FC weight pack, row-major (fc3), float4 reads.
__global__ void k_pack_fcw(const float* __restrict__ w, u32* __restrict__ pw,
                           int O, int K) {
  int KW = K >> 5;
  int idx = blockIdx.x * blockDim.x + threadIdx.x;
  if (idx >= O * KW) return;
  int kw = idx % KW, o = idx / KW;
  const float4* src = (const float4*)(w + (size_t)o * K + kw * 32);
  u32 word = 0;
#pragma unroll
  for (int b4 = 0; b4 < 8; ++b4) {
    float4 f = src[b4];
    word |= (f.x < 0.0f ? 1u : 0u) << (b4 * 4 + 0);
    word |= (f.y < 0.0f ? 1u : 0u) << (b4 * 4 + 1);
    word |= (f.z < 0.0f ? 1u : 0u) << (b4 * 4 + 2);
    word |= (f.w < 0.0f ? 1u : 0u) << (b4 * 4 + 3);
  }
  pw[idx] = word;
}

// ---------------------------------------------------------------------------
// conv1: fp32 x [64][3][32][32], binarized w1, +b1, stoch_act key0.
// Output PLANAR packed: a1[(n*4 + w)*1024 + y*32 + x]. One wave per (n,y,x).
// ---------------------------------------------------------------------------
__global__ __launch_bounds__(256) void k_conv1(
    const float* __restrict__ x, const float* __restrict__ w1,
    const float* __restrict__ b1, u32 k0, u32 k1, u32* __restrict__ out) {
  int wave = (blockIdx.x * 256 + threadIdx.x) >> 6;
  int lane = threadIdx.x & 63;
  int n = wave >> 10;
  int rem = wave & 1023;
  int y = rem >> 5, xx = rem & 31;

  float xv[27];
#pragma unroll
  for (int ci = 0; ci < 3; ++ci)
#pragma unroll
    for (int dy = -1; dy <= 1; ++dy)
#pragma unroll
      for (int dx = -1; dx <= 1; ++dx) {
        int gy = y + dy, gx = xx + dx;
        float v = 0.0f;
        if ((unsigned)gy < 32u && (unsigned)gx < 32u)
          v = x[((n * 3 + ci) * 32 + gy) * 32 + gx];
        xv[(ci * 3 + (dy + 1)) * 3 + (dx + 1)] = v;
      }

  u64 bm[2];
#pragma unroll
  for (int h = 0; h < 2; ++h) {
    int co = lane + h * 64;
    float acc = 0.0f;
#pragma unroll
    for (int kh = 0; kh < 3; ++kh)
#pragma unroll
      for (int kw = 0; kw < 3; ++kw)
#pragma unroll
        for (int ci = 0; ci < 3; ++ci) {
          int k = (ci * 3 + kh) * 3 + kw;
          float wv = w1[co * 27 + k];
          acc += (wv < 0.0f) ? -xv[k] : xv[k];
        }
    float yv = acc + b1[co];
    u32 j = ((u32)(n * 128 + co) << 10) | (u32)(y << 5) | (u32)xx;
    bm[h] = __ballot(act_neg(yv, k0, k1, j));
  }
  if (lane < 4) {
    u32 wsel = (lane & 1) ? (u32)(bm[lane >> 1] >> 32) : (u32)bm[lane >> 1];
    out[(u32)(n * 4 + lane) * 1024u + (u32)(y * 32 + xx)] = wsel;
  }
}

// ---------------------------------------------------------------------------
// Binary conv via i8 MFMA (layers 2..6), v10 — r12-proven structure.
// ---------------------------------------------------------------------------
template <int W>
__global__ __launch_bounds__(256) void k_bconv9(
    const u32* __restrict__ in, const u32* __restrict__ bfrag,
    const float* __restrict__ bias, int Cout, u32 k0, u32 k1,
    u32* __restrict__ out) {
  const int tid = threadIdx.x;
  const int lane = tid & 63;
  const int wv = tid >> 6;
  const int n = blockIdx.x;
  const int y0 = blockIdx.y * 4;
  const int cot = blockIdx.z * 4 + wv;
  const int WOUT = Cout >> 5;

  __shared__ u32 sl[2][8 * 6 * 36];

  // Expand-item geometry: item = (row r, x col xc); 204 active threads.
  const int er = tid / 34;
  const int exc = tid % 34;
  const bool eact = tid < 204;
  const int egy = y0 - 1 + er;
  const int egx = exc - 1;
  const bool ein =
      eact && ((unsigned)egy < 32u) && ((unsigned)egx < 32u);

  v16i acc[4];
#pragma unroll
  for (int r = 0; r < 4; ++r)
#pragma unroll
    for (int e = 0; e < 16; ++e) acc[r][e] = 0;

  // Prologue: stage slice 0 (OOB cells = true i8 zero).
  {
    u32 word = ein ? in[(u32)(n * W) * 1024u + (u32)(egy * 32 + egx)] : 0u;
    if (eact) {
      u32* base = &sl[0][er * 36 + exc];
#pragma unroll
      for (int cd = 0; cd < 8; ++cd) {
        u32 nib = (word >> (cd * 4)) & 0xFu;
        u32 spread = (nib * 0x00204081u) & 0x01010101u;
        u32 val = (spread * 0xFEu) ^ 0x01010101u;
        base[cd * 216] = ein ? val : 0u;
      }
    }
  }
  __syncthreads();

#pragma unroll 1
  for (int kt = 0; kt < W; ++kt) {
    const int cur = kt & 1;
    // Early-issue next slice's global load (hides under af reads + MFMA).
    u32 wn = 0;
    if (kt + 1 < W && ein)
      wn = in[(u32)(n * W + kt + 1) * 1024u + (u32)(egy * 32 + egx)];

    // Load the 18 distinct A-fragments (conflict-free b32 reads).
    v4i af[18];
    const int xb = lane & 31;
    const int cd0 = (lane >> 5) * 4;
    const u32* slc = sl[cur];
#pragma unroll
    for (int sr = 0; sr < 6; ++sr)
#pragma unroll
      for (int dxx = 0; dxx < 3; ++dxx)
#pragma unroll
        for (int q = 0; q < 4; ++q)
          af[sr * 3 + dxx][q] =
              (int)slc[((cd0 + q) * 6 + sr) * 36 + xb + dxx];

    const u32* bptr = bfrag + ((size_t)(cot * W + kt) * 9) * 256 + lane * 4;
#pragma unroll
    for (int t = 0; t < 9; ++t) {
      v4i B = *(const v4i*)(bptr + t * 256);
      const int dy = t / 3 - 1, dxx = t % 3;
#pragma unroll
      for (int r = 0; r < 4; ++r)
        acc[r] = __builtin_amdgcn_mfma_i32_32x32x32_i8(
            af[(r + dy + 1) * 3 + dxx], B, acc[r], 0, 0, 0);
    }

    // Expand-write next slice (OOB cells = true i8 zero).
    if (kt + 1 < W && eact) {
      u32* base = &sl[cur ^ 1][er * 36 + exc];
#pragma unroll
      for (int cd = 0; cd < 8; ++cd) {
        u32 nib = (wn >> (cd * 4)) & 0xFu;
        u32 spread = (nib * 0x00204081u) & 0x01010101u;
        u32 val = (spread * 0xFEu) ^ 0x01010101u;
        base[cd * 216] = ein ? val : 0u;
      }
    }
    __syncthreads();
  }

  // Epilogue: bias + stoch_act + ballot-pack into planar channel words.
  const int co = cot * 32 + (lane & 31);
  const float bo = bias[co];
  const u32 jb = (u32)(n * Cout + co) * 1024u;
#pragma unroll
  for (int r = 0; r < 4; ++r) {
    const int y = y0 + r;
#pragma unroll
    for (int reg = 0; reg < 16; ++reg) {
      const int mlo = (reg & 3) + 8 * (reg >> 2);
      const int m = mlo + 4 * (lane >> 5);
      float yv = (float)acc[r][reg] + bo;
      bool neg = act_neg(yv, k0, k1, jb + (u32)(y * 32 + m));
      u64 b = __ballot(neg);
      if (lane == 0)
        out[(u32)(n * WOUT + cot) * 1024u + (u32)(y * 32 + mlo)] = (u32)b;
      else if (lane == 32)
        out[(u32)(n * WOUT + cot) * 1024u + (u32)(y * 32 + mlo + 4)] =
            (u32)(b >> 32);
    }
  }
}

// ---------------------------------------------------------------------------
// Repack conv6 PLANAR output into FC1 row layout (x-packed).
// ---------------------------------------------------------------------------
__global__ void k_repack(const u32* __restrict__ a6, u32* __restrict__ f0) {
  int idx = blockIdx.x * blockDim.x + threadIdx.x;
  if (idx >= 4096 * 256) return;
  int w = idx & 255, r = idx >> 8;
  int n = r >> 6, chi = r & 63;
  int clo = w >> 5, yy = w & 31;
  int c = chi * 8 + clo;
  const u32* base = a6 + (u32)(n * 16 + (c >> 5)) * 1024u + (u32)(yy * 32);
  u32 sh = (u32)(c & 31);
  u32 word = 0;
#pragma unroll
  for (int xp = 0; xp < 32; ++xp)
    word |= ((base[xp] >> sh) & 1u) << xp;
  f0[idx] = word;
}

// ---------------------------------------------------------------------------
// Binary FC with transposed weights (proven round 4). Block 256 = 4 waves;
// 32 rows (LDS) x 64 outputs; wave handles 8 rows; lane = o.
// ---------------------------------------------------------------------------
template <int KW>
__global__ __launch_bounds__(256, 4) void k_fct(
    const u32* __restrict__ in, const u32* __restrict__ pwT,
    const float* __restrict__ bias, int O, u32 k0, u32 k1,
    u32* __restrict__ out) {
  const int tid = threadIdx.x, lane = tid & 63;
  const int wv = __builtin_amdgcn_readfirstlane(tid >> 6);
  const int rbase = blockIdx.x * 32;
  const int obase = blockIdx.y * 64;
  __shared__ __align__(16) u32 rows[32 * KW];
  for (int i = tid; i < 32 * KW; i += 256)
    rows[i] = in[(size_t)(rbase + i / KW) * KW + (i % KW)];
  __syncthreads();

  const int o = obase + lane;
  const int r0 = wv * 8;
  u32 acc[8];
#pragma unroll
  for (int rr = 0; rr < 8; ++rr) acc[rr] = 0;
  for (int k4 = 0; k4 < KW / 4; ++k4) {
    uint4 w4 = ((const uint4*)pwT)[(size_t)k4 * O + o];
#pragma unroll
    for (int rr = 0; rr < 8; ++rr) {
      uint4 av = *(const uint4*)&rows[(r0 + rr) * KW + k4 * 4];
      acc[rr] += __popc(av.x ^ w4.x) + __popc(av.y ^ w4.y) +
                 __popc(av.z ^ w4.z) + __popc(av.w ^ w4.w);
    }
  }
  const int OW = O >> 5;
  const float bo = bias[o];
#pragma unroll
  for (int rr = 0; rr < 8; ++rr) {
    int r = rbase + r0 + rr;
    float yv = (float)(KW * 32 - 2 * (int)acc[rr]) + bo;
    bool neg = act_neg(yv, k0, k1, (u32)r * (u32)O + (u32)o);
    u64 b = __ballot(neg);
    if (lane == 0) {
      out[(size_t)r * OW + (obase >> 5)] = (u32)b;
      out[(size_t)r * OW + (obase >> 5) + 1] = (u32)(b >> 32);
    }
  }
}

// FC3: [4096][32 words] x [10][32 words] -> fp32 +-1 output [4096][10].
__global__ __launch_bounds__(64) void k_fc3(
    const u32* __restrict__ in, const u32* __restrict__ pw,
    const float* __restrict__ bias, u32 k0, u32 k1,
    float* __restrict__ outp) {
  const int lane = threadIdx.x;
  const int r = blockIdx.x;
  __shared__ u32 row[32];
  if (lane < 32) row[lane] = in[(size_t)r * 32 + lane];
  __syncthreads();
  if (lane < 10) {
    int acc = 0;
#pragma unroll
    for (int k = 0; k < 32; ++k) acc += __popc(row[k] ^ pw[lane * 32 + k]);
    float yv = (float)(1024 - 2 * acc) + bias[lane];
    bool neg = act_neg(yv, k0, k1, (u32)r * 10u + (u32)lane);
    outp[(size_t)r * 10 + lane] = neg ? -1.0f : 1.0f;
  }
}

// ---------------------------------------------------------------------------
extern "C" void kernel_launch(void* const* d_in, const int* in_sizes, int n_in,
                              void* d_out, int out_size, void* d_ws,
                              size_t ws_size, hipStream_t stream) {
  const float* x   = (const float*)d_in[0];
  const float* w1  = (const float*)d_in[1];
  const float* b1  = (const float*)d_in[2];
  const float* w2  = (const float*)d_in[3];
  const float* b2  = (const float*)d_in[4];
  const float* w3  = (const float*)d_in[5];
  const float* b3  = (const float*)d_in[6];
  const float* w4  = (const float*)d_in[7];
  const float* b4  = (const float*)d_in[8];
  const float* w5  = (const float*)d_in[9];
  const float* b5  = (const float*)d_in[10];
  const float* w6  = (const float*)d_in[11];
  const float* b6  = (const float*)d_in[12];
  const float* fw1 = (const float*)d_in[13];
  const float* fb1 = (const float*)d_in[14];
  const float* fw2 = (const float*)d_in[15];
  const float* fb2 = (const float*)d_in[16];
  const float* fw3 = (const float*)d_in[17];
  const float* fb3 = (const float*)d_in[18];

  u32 K[9][2];
  for (int i = 0; i < 9; ++i) tf2x32(0u, 42u, 0u, (u32)i, K[i][0], K[i][1]);

  char* ws = (char*)d_ws;
  size_t off = 0;
  auto alloc = [&](size_t bytes) -> char* {
    char* p = ws + off;
    off += (bytes + 255) & ~(size_t)255;
    return p;
  };
  // i8 MFMA weight fragment buffers: Cout*9*Cin bytes each.
  u32* bf2  = (u32*)alloc(256u * 9 * 128);
  u32* bf3  = (u32*)alloc(256u * 9 * 256);
  u32* bf4  = (u32*)alloc(256u * 9 * 256);
  u32* bf5  = (u32*)alloc(512u * 9 * 256);
  u32* bf6  = (u32*)alloc(512u * 9 * 512);
  u32* pfw1 = (u32*)alloc(1024u * 256 * 4);
  u32* pfw2 = (u32*)alloc(1024u * 32 * 4);
  u32* pfw3 = (u32*)alloc(10u * 32 * 4);
  u32* a1   = (u32*)alloc(64u * 1024 * 4 * 4);
  u32* a2   = (u32*)alloc(64u * 1024 * 8 * 4);
  u32* a3   = (u32*)alloc(64u * 1024 * 8 * 4);
  u32* a4   = (u32*)alloc(64u * 1024 * 8 * 4);
  u32* a5   = (u32*)alloc(64u * 1024 * 16 * 4);
  u32* a6   = (u32*)alloc(64u * 1024 * 16 * 4);
  u32* f0   = (u32*)alloc(4096u * 256 * 4);
  u32* f1   = (u32*)alloc(4096u * 32 * 4);
  u32* f2   = (u32*)alloc(4096u * 32 * 4);
  (void)ws_size;  // ~27 MB of workspace

  int t;
  t = (256 / 32) * 4 * 9 * 256;
  k_pack_wfrag<<<(t + 255) / 256, 256, 0, stream>>>(w2, bf2, 256, 128);
  t = (256 / 32) * 8 * 9 * 256;
  k_pack_wfrag<<<(t + 255) / 256, 256, 0, stream>>>(w3, bf3, 256, 256);
  k_pack_wfrag<<<(t + 255) / 256, 256, 0, stream>>>(w4, bf4, 256, 256);
  t = (512 / 32) * 8 * 9 * 256;
  k_pack_wfrag<<<(t + 255) / 256, 256, 0, stream>>>(w5, bf5, 512, 256);
  t = (512 / 32) * 16 * 9 * 256;
  k_pack_wfrag<<<(t + 255) / 256, 256, 0, stream>>>(w6, bf6, 512, 512);
  t = 1024 * 256;
  k_pack_fcwT<<<(t + 255) / 256, 256, 0, stream>>>(fw1, pfw1, 1024, 8192);
  t = 1024 * 32;
  k_pack_fcwT<<<(t + 255) / 256, 256, 0, stream>>>(fw2, pfw2, 1024, 1024);
  t = 10 * 32;
  k_pack_fcw<<<(t + 255) / 256, 256, 0, stream>>>(fw3, pfw3, 10, 1024);

  k_conv1<<<16384, 256, 0, stream>>>(x, w1, b1, K[0][0], K[0][1], a1);
  k_bconv9<4><<<dim3(64, 8, 2), 256, 0, stream>>>(a1, bf2, b2, 256,
                                                  K[1][0], K[1][1], a2);
  k_bconv9<8><<<dim3(64, 8, 2), 256, 0, stream>>>(a2, bf3, b3, 256,
                                                  K[2][0], K[2][1], a3);
  k_bconv9<8><<<dim3(64, 8, 2), 256, 0, stream>>>(a3, bf4, b4, 256,
                                                  K[3][0], K[3][1], a4);
  k_bconv9<8><<<dim3(64, 8, 4), 256, 0, stream>>>(a4, bf5, b5, 512,
                                                  K[4][0], K[4][1], a5);
  k_bconv9<16><<<dim3(64, 8, 4), 256, 0, stream>>>(a5, bf6, b6, 512,
                                                   K[5][0], K[5][1], a6);
  k_repack<<<(4096 * 256 + 255) / 256, 256, 0, stream>>>(a6, f0);
  k_fct<256><<<dim3(128, 16), 256, 0, stream>>>(f0, pfw1, fb1, 1024,
                                                K[6][0], K[6][1], f1);
  k_fct<32><<<dim3(128, 16), 256, 0, stream>>>(f1, pfw2, fb2, 1024,
                                               K[7][0], K[7][1], f2);
  k_fc3<<<4096, 64, 0, stream>>>(f2, pfw3, fb3, K[8][0], K[8][1],
                                 (float*)d_out);
}

// Round 14
// 691.965 us; speedup vs baseline: 1.9017x; 1.0234x over previous
//
#include <hip/hip_runtime.h>
#include <stdint.h>

typedef unsigned int u32;
typedef unsigned long long u64;
typedef int v4i __attribute__((ext_vector_type(4)));
typedef int v16i __attribute__((ext_vector_type(16)));

// ---------------------------------------------------------------------------
// Threefry-2x32, 20 rounds — bit-exact replica of JAX's threefry2x32 primitive.
// ---------------------------------------------------------------------------
__host__ __device__ __forceinline__ void tf2x32(u32 k0, u32 k1, u32 x0, u32 x1,
                                                u32& o0, u32& o1) {
  u32 k2 = k0 ^ k1 ^ 0x1BD11BDAu;
  x0 += k0; x1 += k1;
#ifdef __HIP_DEVICE_COMPILE__
#define ROTL(v, r) __builtin_rotateleft32((v), (r))
#else
#define ROTL(v, r) (((v) << (r)) | ((v) >> (32 - (r))))
#endif
#define TFR(r) { x0 += x1; x1 = ROTL(x1, r); x1 ^= x0; }
  TFR(13) TFR(15) TFR(26) TFR(6)   x0 += k1; x1 += k2 + 1u;
  TFR(17) TFR(29) TFR(16) TFR(24)  x0 += k2; x1 += k0 + 2u;
  TFR(13) TFR(15) TFR(26) TFR(6)   x0 += k0; x1 += k1 + 3u;
  TFR(17) TFR(29) TFR(16) TFR(24)  x0 += k1; x1 += k2 + 4u;
  TFR(13) TFR(15) TFR(26) TFR(6)   x0 += k2; x1 += k0 + 5u;
#undef TFR
#undef ROTL
  o0 = x0; o1 = x1;
}

// stoch_act decision, clip-free (exact; see r13): out = -1 iff !(2u < y+1).
__device__ __forceinline__ bool act_neg(float y, u32 k0, u32 k1, u32 j) {
  u32 o0, o1;
  tf2x32(k0, k1, 0u, j, o0, o1);
  u32 bits = o0 ^ o1;
  float uf = __uint_as_float(0x3f800000u | (bits >> 9));
  float u2 = __builtin_fmaf(uf, 2.0f, -2.0f);
  float t1 = y + 1.0f;
  return !(u2 < t1);
}

// ---------------------------------------------------------------------------
// Conv weight pack directly into i8 MFMA B-fragment order.
// bf[((cot*W + kt)*9 + t)*256 + l*4 + i4], bytes b:
//   co = cot*32 + (l&31), ci = kt*32 + (l>>5)*16 + i4*4 + b, tap t.
// i8 = +1 if w>=0 else -1 (0x01 / 0xFF).
// ---------------------------------------------------------------------------
__global__ void k_pack_wfrag(const float* __restrict__ w, u32* __restrict__ bf,
                             int Cout, int Cin) {
  const int W = Cin >> 5;
  const int total = (Cout >> 5) * W * 9 * 256;
  int idx = blockIdx.x * blockDim.x + threadIdx.x;
  if (idx >= total) return;
  int i4 = idx & 3;
  int l = (idx >> 2) & 63;
  int t = (idx >> 8) % 9;
  int kt = (idx / 2304) % W;
  int cot = idx / (2304 * W);
  int co = cot * 32 + (l & 31);
  int ci0 = kt * 32 + (l >> 5) * 16 + i4 * 4;
  int kh = t / 3, kw = t % 3;
  u32 v = 0;
#pragma unroll
  for (int b = 0; b < 4; ++b) {
    float wf = w[((size_t)(co * Cin + ci0 + b) * 3 + kh) * 3 + kw];
    v |= (wf < 0.0f ? 0xFFu : 0x01u) << (8 * b);
  }
  bf[idx] = v;
}

// FC weight pack, transposed for coalesced lane=o loads: pwT[k4][o][j].
__global__ void k_pack_fcwT(const float* __restrict__ w, u32* __restrict__ pwT,
                            int O, int K) {
  int KW = K >> 5;
  int idx = blockIdx.x * blockDim.x + threadIdx.x;
  if (idx >= O * KW) return;
  int kw = idx % KW, o = idx / KW;
  const float4* src = (const float4*)(w + (size_t)o * K + kw * 32);
  u32 word = 0;
#pragma unroll
  for (int b4 = 0; b4 < 8; ++b4) {
    float4 f = src[b4];
    word |= (f.x < 0.0f ? 1u : 0u) << (b4 * 4 + 0);
    word |= (f.y < 0.0f ? 1u : 0u) << (b4 * 4 + 1);
    word |= (f.z < 0.0f ? 1u : 0u) << (b4 * 4 + 2);
    word |= (f.w < 0.0f ? 1u : 0u) << (b4 * 4 + 3);
  }
  int k4 = kw >> 2, j = kw & 3;
  pwT[((size_t)k4 * O + o) * 4 + j] = word;
}

// FC weight pack, row-major (fc3).
__global__ void k_pack_fcw(const float* __restrict__ w, u32* __restrict__ pw,
                           int O, int K) {
  int KW = K >> 5;
  int idx = blockIdx.x * blockDim.x + threadIdx.x;
  if (idx >= O * KW) return;
  int kw = idx % KW, o = idx / KW;
  const float4* src = (const float4*)(w + (size_t)o * K + kw * 32);
  u32 word = 0;
#pragma unroll
  for (int b4 = 0; b4 < 8; ++b4) {
    float4 f = src[b4];
    word |= (f.x < 0.0f ? 1u : 0u) << (b4 * 4 + 0);
    word |= (f.y < 0.0f ? 1u : 0u) << (b4 * 4 + 1);
    word |= (f.z < 0.0f ? 1u : 0u) << (b4 * 4 + 2);
    word |= (f.w < 0.0f ? 1u : 0u) << (b4 * 4 + 3);
  }
  pw[idx] = word;
}

// ---------------------------------------------------------------------------
// conv1: fp32 x [64][3][32][32], binarized w1, +b1, stoch_act key0.
// Output PLANAR packed: a1[(n*4 + w)*1024 + y*32 + x]. One wave per (n,y,x).
// ---------------------------------------------------------------------------
__global__ __launch_bounds__(256) void k_conv1(
    const float* __restrict__ x, const float* __restrict__ w1,
    const float* __restrict__ b1, u32 k0, u32 k1, u32* __restrict__ out) {
  int wave = (blockIdx.x * 256 + threadIdx.x) >> 6;
  int lane = threadIdx.x & 63;
  int n = wave >> 10;
  int rem = wave & 1023;
  int y = rem >> 5, xx = rem & 31;

  float xv[27];
#pragma unroll
  for (int ci = 0; ci < 3; ++ci)
#pragma unroll
    for (int dy = -1; dy <= 1; ++dy)
#pragma unroll
      for (int dx = -1; dx <= 1; ++dx) {
        int gy = y + dy, gx = xx + dx;
        float v = 0.0f;
        if ((unsigned)gy < 32u && (unsigned)gx < 32u)
          v = x[((n * 3 + ci) * 32 + gy) * 32 + gx];
        xv[(ci * 3 + (dy + 1)) * 3 + (dx + 1)] = v;
      }

  u64 bm[2];
#pragma unroll
  for (int h = 0; h < 2; ++h) {
    int co = lane + h * 64;
    float acc = 0.0f;
#pragma unroll
    for (int kh = 0; kh < 3; ++kh)
#pragma unroll
      for (int kw = 0; kw < 3; ++kw)
#pragma unroll
        for (int ci = 0; ci < 3; ++ci) {
          int k = (ci * 3 + kh) * 3 + kw;
          float wv = w1[co * 27 + k];
          acc += (wv < 0.0f) ? -xv[k] : xv[k];
        }
    float yv = acc + b1[co];
    u32 j = ((u32)(n * 128 + co) << 10) | (u32)(y << 5) | (u32)xx;
    bm[h] = __ballot(act_neg(yv, k0, k1, j));
  }
  if (lane < 4) {
    u32 wsel = (lane & 1) ? (u32)(bm[lane >> 1] >> 32) : (u32)bm[lane >> 1];
    out[(u32)(n * 4 + lane) * 1024u + (u32)(y * 32 + xx)] = wsel;
  }
}

// ---------------------------------------------------------------------------
// Binary conv via i8 MFMA (layers 2..6), v11 — r13-proven dataflow; LDS
// traffic b128-ized: slice stored as TWO half-arrays sl[buf][half][6*36*4]
// (half = ci-dwords 0-3 / 4-7 = lane>>5), so
//  - A-fragments are 18 ds_read_b128 per wave-kt (16B-aligned, lane-
//    consecutive) instead of 72 ds_read_b32
//  - expand writes are 2 ds_write_b128 per item instead of 8 strided b32
// Same math, same RNG indices, same OOB-zero semantics.
// ---------------------------------------------------------------------------
template <int W>
__global__ __launch_bounds__(256) void k_bconv10(
    const u32* __restrict__ in, const u32* __restrict__ bfrag,
    const float* __restrict__ bias, int Cout, u32 k0, u32 k1,
    u32* __restrict__ out) {
  const int tid = threadIdx.x;
  const int lane = tid & 63;
  const int wv = tid >> 6;
  const int n = blockIdx.x;
  const int y0 = blockIdx.y * 4;
  const int cot = blockIdx.z * 4 + wv;
  const int WOUT = Cout >> 5;

  __shared__ __align__(16) u32 sl[2][2][6 * 36 * 4];

  // Expand-item geometry: item = (row r, x col xc); 204 active threads.
  const int er = tid / 34;
  const int exc = tid % 34;
  const bool eact = tid < 204;
  const int egy = y0 - 1 + er;
  const int egx = exc - 1;
  const bool ein =
      eact && ((unsigned)egy < 32u) && ((unsigned)egx < 32u);

  v16i acc[4];
#pragma unroll
  for (int r = 0; r < 4; ++r)
#pragma unroll
    for (int e = 0; e < 16; ++e) acc[r][e] = 0;

  // Prologue: stage slice 0 (OOB cells = true i8 zero), b128 writes.
  {
    u32 word = ein ? in[(u32)(n * W) * 1024u + (u32)(egy * 32 + egx)] : 0u;
    if (eact) {
#pragma unroll
      for (int h = 0; h < 2; ++h) {
        v4i v;
#pragma unroll
        for (int q = 0; q < 4; ++q) {
          u32 nib = (word >> ((4 * h + q) * 4)) & 0xFu;
          u32 spread = (nib * 0x00204081u) & 0x01010101u;
          u32 val = (spread * 0xFEu) ^ 0x01010101u;
          v[q] = ein ? (int)val : 0;
        }
        *(v4i*)&sl[0][h][(er * 36 + exc) * 4] = v;
      }
    }
  }
  __syncthreads();

#pragma unroll 1
  for (int kt = 0; kt < W; ++kt) {
    const int cur = kt & 1;
    // Early-issue next slice's global load (hides under af reads + MFMA).
    u32 wn = 0;
    if (kt + 1 < W && ein)
      wn = in[(u32)(n * W + kt + 1) * 1024u + (u32)(egy * 32 + egx)];

    // Load the 18 distinct A-fragments as aligned b128 reads.
    v4i af[18];
    const int xb = lane & 31;
    const u32* slc = sl[cur][lane >> 5];
#pragma unroll
    for (int sr = 0; sr < 6; ++sr)
#pragma unroll
      for (int dxx = 0; dxx < 3; ++dxx)
        af[sr * 3 + dxx] = *(const v4i*)&slc[(sr * 36 + xb + dxx) * 4];

    const u32* bptr = bfrag + ((size_t)(cot * W + kt) * 9) * 256 + lane * 4;
#pragma unroll
    for (int t = 0; t < 9; ++t) {
      v4i B = *(const v4i*)(bptr + t * 256);
      const int dy = t / 3 - 1, dxx = t % 3;
#pragma unroll
      for (int r = 0; r < 4; ++r)
        acc[r] = __builtin_amdgcn_mfma_i32_32x32x32_i8(
            af[(r + dy + 1) * 3 + dxx], B, acc[r], 0, 0, 0);
    }

    // Expand-write next slice (OOB cells = true i8 zero), b128 writes.
    if (kt + 1 < W && eact) {
#pragma unroll
      for (int h = 0; h < 2; ++h) {
        v4i v;
#pragma unroll
        for (int q = 0; q < 4; ++q) {
          u32 nib = (wn >> ((4 * h + q) * 4)) & 0xFu;
          u32 spread = (nib * 0x00204081u) & 0x01010101u;
          u32 val = (spread * 0xFEu) ^ 0x01010101u;
          v[q] = ein ? (int)val : 0;
        }
        *(v4i*)&sl[cur ^ 1][h][(er * 36 + exc) * 4] = v;
      }
    }
    __syncthreads();
  }

  // Epilogue: bias + stoch_act + ballot-pack into planar channel words.
  const int co = cot * 32 + (lane & 31);
  const float bo = bias[co];
  const u32 jb = (u32)(n * Cout + co) * 1024u;
#pragma unroll
  for (int r = 0; r < 4; ++r) {
    const int y = y0 + r;
#pragma unroll
    for (int reg = 0; reg < 16; ++reg) {
      const int mlo = (reg & 3) + 8 * (reg >> 2);
      const int m = mlo + 4 * (lane >> 5);
      float yv = (float)acc[r][reg] + bo;
      bool neg = act_neg(yv, k0, k1, jb + (u32)(y * 32 + m));
      u64 b = __ballot(neg);
      if (lane == 0)
        out[(u32)(n * WOUT + cot) * 1024u + (u32)(y * 32 + mlo)] = (u32)b;
      else if (lane == 32)
        out[(u32)(n * WOUT + cot) * 1024u + (u32)(y * 32 + mlo + 4)] =
            (u32)(b >> 32);
    }
  }
}

// ---------------------------------------------------------------------------
// Repack conv6 PLANAR output into FC1 row layout (x-packed).
// ---------------------------------------------------------------------------
__global__ void k_repack(const u32* __restrict__ a6, u32* __restrict__ f0) {
  int idx = blockIdx.x * blockDim.x + threadIdx.x;
  if (idx >= 4096 * 256) return;
  int w = idx & 255, r = idx >> 8;
  int n = r >> 6, chi = r & 63;
  int clo = w >> 5, yy = w & 31;
  int c = chi * 8 + clo;
  const u32* base = a6 + (u32)(n * 16 + (c >> 5)) * 1024u + (u32)(yy * 32);
  u32 sh = (u32)(c & 31);
  u32 word = 0;
#pragma unroll
  for (int xp = 0; xp < 32; ++xp)
    word |= ((base[xp] >> sh) & 1u) << xp;
  f0[idx] = word;
}

// ---------------------------------------------------------------------------
// Binary FC with transposed weights (proven round 4). Block 256 = 4 waves;
// 32 rows (LDS) x 64 outputs; wave handles 8 rows; lane = o.
// ---------------------------------------------------------------------------
template <int KW>
__global__ __launch_bounds__(256, 4) void k_fct(
    const u32* __restrict__ in, const u32* __restrict__ pwT,
    const float* __restrict__ bias, int O, u32 k0, u32 k1,
    u32* __restrict__ out) {
  const int tid = threadIdx.x, lane = tid & 63;
  const int wv = __builtin_amdgcn_readfirstlane(tid >> 6);
  const int rbase = blockIdx.x * 32;
  const int obase = blockIdx.y * 64;
  __shared__ __align__(16) u32 rows[32 * KW];
  for (int i = tid; i < 32 * KW; i += 256)
    rows[i] = in[(size_t)(rbase + i / KW) * KW + (i % KW)];
  __syncthreads();

  const int o = obase + lane;
  const int r0 = wv * 8;
  u32 acc[8];
#pragma unroll
  for (int rr = 0; rr < 8; ++rr) acc[rr] = 0;
  for (int k4 = 0; k4 < KW / 4; ++k4) {
    uint4 w4 = ((const uint4*)pwT)[(size_t)k4 * O + o];
#pragma unroll
    for (int rr = 0; rr < 8; ++rr) {
      uint4 av = *(const uint4*)&rows[(r0 + rr) * KW + k4 * 4];
      acc[rr] += __popc(av.x ^ w4.x) + __popc(av.y ^ w4.y) +
                 __popc(av.z ^ w4.z) + __popc(av.w ^ w4.w);
    }
  }
  const int OW = O >> 5;
  const float bo = bias[o];
#pragma unroll
  for (int rr = 0; rr < 8; ++rr) {
    int r = rbase + r0 + rr;
    float yv = (float)(KW * 32 - 2 * (int)acc[rr]) + bo;
    bool neg = act_neg(yv, k0, k1, (u32)r * (u32)O + (u32)o);
    u64 b = __ballot(neg);
    if (lane == 0) {
      out[(size_t)r * OW + (obase >> 5)] = (u32)b;
      out[(size_t)r * OW + (obase >> 5) + 1] = (u32)(b >> 32);
    }
  }
}

// FC3: [4096][32 words] x [10][32 words] -> fp32 +-1 output [4096][10].
__global__ __launch_bounds__(64) void k_fc3(
    const u32* __restrict__ in, const u32* __restrict__ pw,
    const float* __restrict__ bias, u32 k0, u32 k1,
    float* __restrict__ outp) {
  const int lane = threadIdx.x;
  const int r = blockIdx.x;
  __shared__ u32 row[32];
  if (lane < 32) row[lane] = in[(size_t)r * 32 + lane];
  __syncthreads();
  if (lane < 10) {
    int acc = 0;
#pragma unroll
    for (int k = 0; k < 32; ++k) acc += __popc(row[k] ^ pw[lane * 32 + k]);
    float yv = (float)(1024 - 2 * acc) + bias[lane];
    bool neg = act_neg(yv, k0, k1, (u32)r * 10u + (u32)lane);
    outp[(size_t)r * 10 + lane] = neg ? -1.0f : 1.0f;
  }
}

// ---------------------------------------------------------------------------
extern "C" void kernel_launch(void* const* d_in, const int* in_sizes, int n_in,
                              void* d_out, int out_size, void* d_ws,
                              size_t ws_size, hipStream_t stream) {
  const float* x   = (const float*)d_in[0];
  const float* w1  = (const float*)d_in[1];
  const float* b1  = (const float*)d_in[2];
  const float* w2  = (const float*)d_in[3];
  const float* b2  = (const float*)d_in[4];
  const float* w3  = (const float*)d_in[5];
  const float* b3  = (const float*)d_in[6];
  const float* w4  = (const float*)d_in[7];
  const float* b4  = (const float*)d_in[8];
  const float* w5  = (const float*)d_in[9];
  const float* b5  = (const float*)d_in[10];
  const float* w6  = (const float*)d_in[11];
  const float* b6  = (const float*)d_in[12];
  const float* fw1 = (const float*)d_in[13];
  const float* fb1 = (const float*)d_in[14];
  const float* fw2 = (const float*)d_in[15];
  const float* fb2 = (const float*)d_in[16];
  const float* fw3 = (const float*)d_in[17];
  const float* fb3 = (const float*)d_in[18];

  u32 K[9][2];
  for (int i = 0; i < 9; ++i) tf2x32(0u, 42u, 0u, (u32)i, K[i][0], K[i][1]);

  char* ws = (char*)d_ws;
  size_t off = 0;
  auto alloc = [&](size_t bytes) -> char* {
    char* p = ws + off;
    off += (bytes + 255) & ~(size_t)255;
    return p;
  };
  // i8 MFMA weight fragment buffers: Cout*9*Cin bytes each.
  u32* bf2  = (u32*)alloc(256u * 9 * 128);
  u32* bf3  = (u32*)alloc(256u * 9 * 256);
  u32* bf4  = (u32*)alloc(256u * 9 * 256);
  u32* bf5  = (u32*)alloc(512u * 9 * 256);
  u32* bf6  = (u32*)alloc(512u * 9 * 512);
  u32* pfw1 = (u32*)alloc(1024u * 256 * 4);
  u32* pfw2 = (u32*)alloc(1024u * 32 * 4);
  u32* pfw3 = (u32*)alloc(10u * 32 * 4);
  u32* a1   = (u32*)alloc(64u * 1024 * 4 * 4);
  u32* a2   = (u32*)alloc(64u * 1024 * 8 * 4);
  u32* a3   = (u32*)alloc(64u * 1024 * 8 * 4);
  u32* a4   = (u32*)alloc(64u * 1024 * 8 * 4);
  u32* a5   = (u32*)alloc(64u * 1024 * 16 * 4);
  u32* a6   = (u32*)alloc(64u * 1024 * 16 * 4);
  u32* f0   = (u32*)alloc(4096u * 256 * 4);
  u32* f1   = (u32*)alloc(4096u * 32 * 4);
  u32* f2   = (u32*)alloc(4096u * 32 * 4);
  (void)ws_size;  // ~27 MB of workspace

  int t;
  t = (256 / 32) * 4 * 9 * 256;
  k_pack_wfrag<<<(t + 255) / 256, 256, 0, stream>>>(w2, bf2, 256, 128);
  t = (256 / 32) * 8 * 9 * 256;
  k_pack_wfrag<<<(t + 255) / 256, 256, 0, stream>>>(w3, bf3, 256, 256);
  k_pack_wfrag<<<(t + 255) / 256, 256, 0, stream>>>(w4, bf4, 256, 256);
  t = (512 / 32) * 8 * 9 * 256;
  k_pack_wfrag<<<(t + 255) / 256, 256, 0, stream>>>(w5, bf5, 512, 256);
  t = (512 / 32) * 16 * 9 * 256;
  k_pack_wfrag<<<(t + 255) / 256, 256, 0, stream>>>(w6, bf6, 512, 512);
  t = 1024 * 256;
  k_pack_fcwT<<<(t + 255) / 256, 256, 0, stream>>>(fw1, pfw1, 1024, 8192);
  t = 1024 * 32;
  k_pack_fcwT<<<(t + 255) / 256, 256, 0, stream>>>(fw2, pfw2, 1024, 1024);
  t = 10 * 32;
  k_pack_fcw<<<(t + 255) / 256, 256, 0, stream>>>(fw3, pfw3, 10, 1024);

  k_conv1<<<16384, 256, 0, stream>>>(x, w1, b1, K[0][0], K[0][1], a1);
  k_bconv10<4><<<dim3(64, 8, 2), 256, 0, stream>>>(a1, bf2, b2, 256,
                                                   K[1][0], K[1][1], a2);
  k_bconv10<8><<<dim3(64, 8, 2), 256, 0, stream>>>(a2, bf3, b3, 256,
                                                   K[2][0], K[2][1], a3);
  k_bconv10<8><<<dim3(64, 8, 2), 256, 0, stream>>>(a3, bf4, b4, 256,
                                                   K[3][0], K[3][1], a4);
  k_bconv10<8><<<dim3(64, 8, 4), 256, 0, stream>>>(a4, bf5, b5, 512,
                                                   K[4][0], K[4][1], a5);
  k_bconv10<16><<<dim3(64, 8, 4), 256, 0, stream>>>(a5, bf6, b6, 512,
                                                    K[5][0], K[5][1], a6);
  k_repack<<<(4096 * 256 + 255) / 256, 256, 0, stream>>>(a6, f0);
  k_fct<256><<<dim3(128, 16), 256, 0, stream>>>(f0, pfw1, fb1, 1024,
                                                K[6][0], K[6][1], f1);
  k_fct<32><<<dim3(128, 16), 256, 0, stream>>>(f1, pfw2, fb2, 1024,
                                               K[7][0], K[7][1], f2);
  k_fc3<<<4096, 64, 0, stream>>>(f2, pfw3, fb3, K[8][0], K[8][1],
                                 (float*)d_out);
}

// Round 15
// 647.074 us; speedup vs baseline: 2.0336x; 1.0694x over previous
//
#include <hip/hip_runtime.h>
#include <stdint.h>

typedef unsigned int u32;
typedef unsigned long long u64;
typedef int v4i __attribute__((ext_vector_type(4)));
typedef int v16i __attribute__((ext_vector_type(16)));

// ---------------------------------------------------------------------------
// Threefry-2x32, 20 rounds — bit-exact replica of JAX's threefry2x32 primitive.
// ---------------------------------------------------------------------------
__host__ __device__ __forceinline__ void tf2x32(u32 k0, u32 k1, u32 x0, u32 x1,
                                                u32& o0, u32& o1) {
  u32 k2 = k0 ^ k1 ^ 0x1BD11BDAu;
  x0 += k0; x1 += k1;
#ifdef __HIP_DEVICE_COMPILE__
#define ROTL(v, r) __builtin_rotateleft32((v), (r))
#else
#define ROTL(v, r) (((v) << (r)) | ((v) >> (32 - (r))))
#endif
#define TFR(r) { x0 += x1; x1 = ROTL(x1, r); x1 ^= x0; }
  TFR(13) TFR(15) TFR(26) TFR(6)   x0 += k1; x1 += k2 + 1u;
  TFR(17) TFR(29) TFR(16) TFR(24)  x0 += k2; x1 += k0 + 2u;
  TFR(13) TFR(15) TFR(26) TFR(6)   x0 += k0; x1 += k1 + 3u;
  TFR(17) TFR(29) TFR(16) TFR(24)  x0 += k1; x1 += k2 + 4u;
  TFR(13) TFR(15) TFR(26) TFR(6)   x0 += k2; x1 += k0 + 5u;
#undef TFR
#undef ROTL
  o0 = x0; o1 = x1;
}

// stoch_act decision, clip-free (exact; see r13): out = -1 iff !(2u < y+1).
__device__ __forceinline__ bool act_neg(float y, u32 k0, u32 k1, u32 j) {
  u32 o0, o1;
  tf2x32(k0, k1, 0u, j, o0, o1);
  u32 bits = o0 ^ o1;
  float uf = __uint_as_float(0x3f800000u | (bits >> 9));
  float u2 = __builtin_fmaf(uf, 2.0f, -2.0f);
  float t1 = y + 1.0f;
  return !(u2 < t1);
}

// ---------------------------------------------------------------------------
// Conv weight pack directly into i8 MFMA B-fragment order.
// bf[((cot*W + kt)*9 + t)*256 + l*4 + i4], bytes b:
//   co = cot*32 + (l&31), ci = kt*32 + (l>>5)*16 + i4*4 + b, tap t.
// i8 = +1 if w>=0 else -1 (0x01 / 0xFF).
// ---------------------------------------------------------------------------
__global__ void k_pack_wfrag(const float* __restrict__ w, u32* __restrict__ bf,
                             int Cout, int Cin) {
  const int W = Cin >> 5;
  const int total = (Cout >> 5) * W * 9 * 256;
  int idx = blockIdx.x * blockDim.x + threadIdx.x;
  if (idx >= total) return;
  int i4 = idx & 3;
  int l = (idx >> 2) & 63;
  int t = (idx >> 8) % 9;
  int kt = (idx / 2304) % W;
  int cot = idx / (2304 * W);
  int co = cot * 32 + (l & 31);
  int ci0 = kt * 32 + (l >> 5) * 16 + i4 * 4;
  int kh = t / 3, kw = t % 3;
  u32 v = 0;
#pragma unroll
  for (int b = 0; b < 4; ++b) {
    float wf = w[((size_t)(co * Cin + ci0 + b) * 3 + kh) * 3 + kw];
    v |= (wf < 0.0f ? 0xFFu : 0x01u) << (8 * b);
  }
  bf[idx] = v;
}

// FC weight pack, transposed for coalesced lane=o loads: pwT[k4][o][j].
__global__ void k_pack_fcwT(const float* __restrict__ w, u32* __restrict__ pwT,
                            int O, int K) {
  int KW = K >> 5;
  int idx = blockIdx.x * blockDim.x + threadIdx.x;
  if (idx >= O * KW) return;
  int kw = idx % KW, o = idx / KW;
  const float4* src = (const float4*)(w + (size_t)o * K + kw * 32);
  u32 word = 0;
#pragma unroll
  for (int b4 = 0; b4 < 8; ++b4) {
    float4 f = src[b4];
    word |= (f.x < 0.0f ? 1u : 0u) << (b4 * 4 + 0);
    word |= (f.y < 0.0f ? 1u : 0u) << (b4 * 4 + 1);
    word |= (f.z < 0.0f ? 1u : 0u) << (b4 * 4 + 2);
    word |= (f.w < 0.0f ? 1u : 0u) << (b4 * 4 + 3);
  }
  int k4 = kw >> 2, j = kw & 3;
  pwT[((size_t)k4 * O + o) * 4 + j] = word;
}

// FC weight pack, row-major (fc3).
__global__ void k_pack_fcw(const float* __restrict__ w, u32* __restrict__ pw,
                           int O, int K) {
  int KW = K >> 5;
  int idx = blockIdx.x * blockDim.x + threadIdx.x;
  if (idx >= O * KW) return;
  int kw = idx % KW, o = idx / KW;
  const float4* src = (const float4*)(w + (size_t)o * K + kw * 32);
  u32 word = 0;
#pragma unroll
  for (int b4 = 0; b4 < 8; ++b4) {
    float4 f = src[b4];
    word |= (f.x < 0.0f ? 1u : 0u) << (b4 * 4 + 0);
    word |= (f.y < 0.0f ? 1u : 0u) << (b4 * 4 + 1);
    word |= (f.z < 0.0f ? 1u : 0u) << (b4 * 4 + 2);
    word |= (f.w < 0.0f ? 1u : 0u) << (b4 * 4 + 3);
  }
  pw[idx] = word;
}

// ---------------------------------------------------------------------------
// conv1: fp32 x [64][3][32][32], binarized w1, +b1, stoch_act key0.
// Output PLANAR packed: a1[(n*4 + w)*1024 + y*32 + x]. One wave per (n,y,x).
// ---------------------------------------------------------------------------
__global__ __launch_bounds__(256) void k_conv1(
    const float* __restrict__ x, const float* __restrict__ w1,
    const float* __restrict__ b1, u32 k0, u32 k1, u32* __restrict__ out) {
  int wave = (blockIdx.x * 256 + threadIdx.x) >> 6;
  int lane = threadIdx.x & 63;
  int n = wave >> 10;
  int rem = wave & 1023;
  int y = rem >> 5, xx = rem & 31;

  float xv[27];
#pragma unroll
  for (int ci = 0; ci < 3; ++ci)
#pragma unroll
    for (int dy = -1; dy <= 1; ++dy)
#pragma unroll
      for (int dx = -1; dx <= 1; ++dx) {
        int gy = y + dy, gx = xx + dx;
        float v = 0.0f;
        if ((unsigned)gy < 32u && (unsigned)gx < 32u)
          v = x[((n * 3 + ci) * 32 + gy) * 32 + gx];
        xv[(ci * 3 + (dy + 1)) * 3 + (dx + 1)] = v;
      }

  u64 bm[2];
#pragma unroll
  for (int h = 0; h < 2; ++h) {
    int co = lane + h * 64;
    float acc = 0.0f;
#pragma unroll
    for (int kh = 0; kh < 3; ++kh)
#pragma unroll
      for (int kw = 0; kw < 3; ++kw)
#pragma unroll
        for (int ci = 0; ci < 3; ++ci) {
          int k = (ci * 3 + kh) * 3 + kw;
          float wv = w1[co * 27 + k];
          acc += (wv < 0.0f) ? -xv[k] : xv[k];
        }
    float yv = acc + b1[co];
    u32 j = ((u32)(n * 128 + co) << 10) | (u32)(y << 5) | (u32)xx;
    bm[h] = __ballot(act_neg(yv, k0, k1, j));
  }
  if (lane < 4) {
    u32 wsel = (lane & 1) ? (u32)(bm[lane >> 1] >> 32) : (u32)bm[lane >> 1];
    out[(u32)(n * 4 + lane) * 1024u + (u32)(y * 32 + xx)] = wsel;
  }
}

// ---------------------------------------------------------------------------
// Binary conv via i8 MFMA (layers 2..6), v12 — r14-proven dataflow; 8 waves
// per block (512 threads) share one staged slice: per-wave expand cost and
// block count halve; wave wv owns cout chunk blockIdx.z*8+wv. Epilogue
// writeback uses a single (lane&31)==0 branch with selected value/address.
// ---------------------------------------------------------------------------
template <int W>
__global__ __launch_bounds__(512) void k_bconv11(
    const u32* __restrict__ in, const u32* __restrict__ bfrag,
    const float* __restrict__ bias, int Cout, u32 k0, u32 k1,
    u32* __restrict__ out) {
  const int tid = threadIdx.x;
  const int lane = tid & 63;
  const int wv = tid >> 6;
  const int n = blockIdx.x;
  const int y0 = blockIdx.y * 4;
  const int cot = blockIdx.z * 8 + wv;
  const int WOUT = Cout >> 5;

  __shared__ __align__(16) u32 sl[2][2][6 * 36 * 4];

  // Expand-item geometry: item = (row r, x col xc); 204 active threads.
  const int er = tid / 34;
  const int exc = tid % 34;
  const bool eact = tid < 204;
  const int egy = y0 - 1 + er;
  const int egx = exc - 1;
  const bool ein =
      eact && ((unsigned)egy < 32u) && ((unsigned)egx < 32u);

  v16i acc[4];
#pragma unroll
  for (int r = 0; r < 4; ++r)
#pragma unroll
    for (int e = 0; e < 16; ++e) acc[r][e] = 0;

  // Prologue: stage slice 0 (OOB cells = true i8 zero), b128 writes.
  {
    u32 word = ein ? in[(u32)(n * W) * 1024u + (u32)(egy * 32 + egx)] : 0u;
    if (eact) {
#pragma unroll
      for (int h = 0; h < 2; ++h) {
        v4i v;
#pragma unroll
        for (int q = 0; q < 4; ++q) {
          u32 nib = (word >> ((4 * h + q) * 4)) & 0xFu;
          u32 spread = (nib * 0x00204081u) & 0x01010101u;
          u32 val = (spread * 0xFEu) ^ 0x01010101u;
          v[q] = ein ? (int)val : 0;
        }
        *(v4i*)&sl[0][h][(er * 36 + exc) * 4] = v;
      }
    }
  }
  __syncthreads();

#pragma unroll 1
  for (int kt = 0; kt < W; ++kt) {
    const int cur = kt & 1;
    // Early-issue next slice's global load (hides under af reads + MFMA).
    u32 wn = 0;
    if (kt + 1 < W && ein)
      wn = in[(u32)(n * W + kt + 1) * 1024u + (u32)(egy * 32 + egx)];

    // Load the 18 distinct A-fragments as aligned b128 reads.
    v4i af[18];
    const int xb = lane & 31;
    const u32* slc = sl[cur][lane >> 5];
#pragma unroll
    for (int sr = 0; sr < 6; ++sr)
#pragma unroll
      for (int dxx = 0; dxx < 3; ++dxx)
        af[sr * 3 + dxx] = *(const v4i*)&slc[(sr * 36 + xb + dxx) * 4];

    const u32* bptr = bfrag + ((size_t)(cot * W + kt) * 9) * 256 + lane * 4;
#pragma unroll
    for (int t = 0; t < 9; ++t) {
      v4i B = *(const v4i*)(bptr + t * 256);
      const int dy = t / 3 - 1, dxx = t % 3;
#pragma unroll
      for (int r = 0; r < 4; ++r)
        acc[r] = __builtin_amdgcn_mfma_i32_32x32x32_i8(
            af[(r + dy + 1) * 3 + dxx], B, acc[r], 0, 0, 0);
    }

    // Expand-write next slice (OOB cells = true i8 zero), b128 writes.
    if (kt + 1 < W && eact) {
#pragma unroll
      for (int h = 0; h < 2; ++h) {
        v4i v;
#pragma unroll
        for (int q = 0; q < 4; ++q) {
          u32 nib = (wn >> ((4 * h + q) * 4)) & 0xFu;
          u32 spread = (nib * 0x00204081u) & 0x01010101u;
          u32 val = (spread * 0xFEu) ^ 0x01010101u;
          v[q] = ein ? (int)val : 0;
        }
        *(v4i*)&sl[cur ^ 1][h][(er * 36 + exc) * 4] = v;
      }
    }
    __syncthreads();
  }

  // Epilogue: bias + stoch_act + ballot-pack into planar channel words.
  const int co = cot * 32 + (lane & 31);
  const float bo = bias[co];
  const u32 jb = (u32)(n * Cout + co) * 1024u;
  const u32 obase = (u32)(n * WOUT + cot) * 1024u + (u32)((lane >> 5) * 4);
#pragma unroll
  for (int r = 0; r < 4; ++r) {
    const int y = y0 + r;
#pragma unroll
    for (int reg = 0; reg < 16; ++reg) {
      const int mlo = (reg & 3) + 8 * (reg >> 2);
      const int m = mlo + 4 * (lane >> 5);
      float yv = (float)acc[r][reg] + bo;
      bool neg = act_neg(yv, k0, k1, jb + (u32)(y * 32 + m));
      u64 b = __ballot(neg);
      if ((lane & 31) == 0) {
        u32 vsel = (lane == 0) ? (u32)b : (u32)(b >> 32);
        out[obase + (u32)(y * 32 + mlo)] = vsel;
      }
    }
  }
}

// ---------------------------------------------------------------------------
// Repack conv6 PLANAR output into FC1 row layout (x-packed).
// ---------------------------------------------------------------------------
__global__ void k_repack(const u32* __restrict__ a6, u32* __restrict__ f0) {
  int idx = blockIdx.x * blockDim.x + threadIdx.x;
  if (idx >= 4096 * 256) return;
  int w = idx & 255, r = idx >> 8;
  int n = r >> 6, chi = r & 63;
  int clo = w >> 5, yy = w & 31;
  int c = chi * 8 + clo;
  const u32* base = a6 + (u32)(n * 16 + (c >> 5)) * 1024u + (u32)(yy * 32);
  u32 sh = (u32)(c & 31);
  u32 word = 0;
#pragma unroll
  for (int xp = 0; xp < 32; ++xp)
    word |= ((base[xp] >> sh) & 1u) << xp;
  f0[idx] = word;
}

// ---------------------------------------------------------------------------
// Binary FC with transposed weights (proven round 4). Block 256 = 4 waves;
// 32 rows (LDS) x 64 outputs; wave handles 8 rows; lane = o.
// ---------------------------------------------------------------------------
template <int KW>
__global__ __launch_bounds__(256, 4) void k_fct(
    const u32* __restrict__ in, const u32* __restrict__ pwT,
    const float* __restrict__ bias, int O, u32 k0, u32 k1,
    u32* __restrict__ out) {
  const int tid = threadIdx.x, lane = tid & 63;
  const int wv = __builtin_amdgcn_readfirstlane(tid >> 6);
  const int rbase = blockIdx.x * 32;
  const int obase = blockIdx.y * 64;
  __shared__ __align__(16) u32 rows[32 * KW];
  for (int i = tid; i < 32 * KW; i += 256)
    rows[i] = in[(size_t)(rbase + i / KW) * KW + (i % KW)];
  __syncthreads();

  const int o = obase + lane;
  const int r0 = wv * 8;
  u32 acc[8];
#pragma unroll
  for (int rr = 0; rr < 8; ++rr) acc[rr] = 0;
  for (int k4 = 0; k4 < KW / 4; ++k4) {
    uint4 w4 = ((const uint4*)pwT)[(size_t)k4 * O + o];
#pragma unroll
    for (int rr = 0; rr < 8; ++rr) {
      uint4 av = *(const uint4*)&rows[(r0 + rr) * KW + k4 * 4];
      acc[rr] += __popc(av.x ^ w4.x) + __popc(av.y ^ w4.y) +
                 __popc(av.z ^ w4.z) + __popc(av.w ^ w4.w);
    }
  }
  const int OW = O >> 5;
  const float bo = bias[o];
#pragma unroll
  for (int rr = 0; rr < 8; ++rr) {
    int r = rbase + r0 + rr;
    float yv = (float)(KW * 32 - 2 * (int)acc[rr]) + bo;
    bool neg = act_neg(yv, k0, k1, (u32)r * (u32)O + (u32)o);
    u64 b = __ballot(neg);
    if (lane == 0) {
      out[(size_t)r * OW + (obase >> 5)] = (u32)b;
      out[(size_t)r * OW + (obase >> 5) + 1] = (u32)(b >> 32);
    }
  }
}

// FC3: [4096][32 words] x [10][32 words] -> fp32 +-1 output [4096][10].
__global__ __launch_bounds__(64) void k_fc3(
    const u32* __restrict__ in, const u32* __restrict__ pw,
    const float* __restrict__ bias, u32 k0, u32 k1,
    float* __restrict__ outp) {
  const int lane = threadIdx.x;
  const int r = blockIdx.x;
  __shared__ u32 row[32];
  if (lane < 32) row[lane] = in[(size_t)r * 32 + lane];
  __syncthreads();
  if (lane < 10) {
    int acc = 0;
#pragma unroll
    for (int k = 0; k < 32; ++k) acc += __popc(row[k] ^ pw[lane * 32 + k]);
    float yv = (float)(1024 - 2 * acc) + bias[lane];
    bool neg = act_neg(yv, k0, k1, (u32)r * 10u + (u32)lane);
    outp[(size_t)r * 10 + lane] = neg ? -1.0f : 1.0f;
  }
}

// ---------------------------------------------------------------------------
extern "C" void kernel_launch(void* const* d_in, const int* in_sizes, int n_in,
                              void* d_out, int out_size, void* d_ws,
                              size_t ws_size, hipStream_t stream) {
  const float* x   = (const float*)d_in[0];
  const float* w1  = (const float*)d_in[1];
  const float* b1  = (const float*)d_in[2];
  const float* w2  = (const float*)d_in[3];
  const float* b2  = (const float*)d_in[4];
  const float* w3  = (const float*)d_in[5];
  const float* b3  = (const float*)d_in[6];
  const float* w4  = (const float*)d_in[7];
  const float* b4  = (const float*)d_in[8];
  const float* w5  = (const float*)d_in[9];
  const float* b5  = (const float*)d_in[10];
  const float* w6  = (const float*)d_in[11];
  const float* b6  = (const float*)d_in[12];
  const float* fw1 = (const float*)d_in[13];
  const float* fb1 = (const float*)d_in[14];
  const float* fw2 = (const float*)d_in[15];
  const float* fb2 = (const float*)d_in[16];
  const float* fw3 = (const float*)d_in[17];
  const float* fb3 = (const float*)d_in[18];

  u32 K[9][2];
  for (int i = 0; i < 9; ++i) tf2x32(0u, 42u, 0u, (u32)i, K[i][0], K[i][1]);

  char* ws = (char*)d_ws;
  size_t off = 0;
  auto alloc = [&](size_t bytes) -> char* {
    char* p = ws + off;
    off += (bytes + 255) & ~(size_t)255;
    return p;
  };
  // i8 MFMA weight fragment buffers: Cout*9*Cin bytes each.
  u32* bf2  = (u32*)alloc(256u * 9 * 128);
  u32* bf3  = (u32*)alloc(256u * 9 * 256);
  u32* bf4  = (u32*)alloc(256u * 9 * 256);
  u32* bf5  = (u32*)alloc(512u * 9 * 256);
  u32* bf6  = (u32*)alloc(512u * 9 * 512);
  u32* pfw1 = (u32*)alloc(1024u * 256 * 4);
  u32* pfw2 = (u32*)alloc(1024u * 32 * 4);
  u32* pfw3 = (u32*)alloc(10u * 32 * 4);
  u32* a1   = (u32*)alloc(64u * 1024 * 4 * 4);
  u32* a2   = (u32*)alloc(64u * 1024 * 8 * 4);
  u32* a3   = (u32*)alloc(64u * 1024 * 8 * 4);
  u32* a4   = (u32*)alloc(64u * 1024 * 8 * 4);
  u32* a5   = (u32*)alloc(64u * 1024 * 16 * 4);
  u32* a6   = (u32*)alloc(64u * 1024 * 16 * 4);
  u32* f0   = (u32*)alloc(4096u * 256 * 4);
  u32* f1   = (u32*)alloc(4096u * 32 * 4);
  u32* f2   = (u32*)alloc(4096u * 32 * 4);
  (void)ws_size;  // ~27 MB of workspace

  int t;
  t = (256 / 32) * 4 * 9 * 256;
  k_pack_wfrag<<<(t + 255) / 256, 256, 0, stream>>>(w2, bf2, 256, 128);
  t = (256 / 32) * 8 * 9 * 256;
  k_pack_wfrag<<<(t + 255) / 256, 256, 0, stream>>>(w3, bf3, 256, 256);
  k_pack_wfrag<<<(t + 255) / 256, 256, 0, stream>>>(w4, bf4, 256, 256);
  t = (512 / 32) * 8 * 9 * 256;
  k_pack_wfrag<<<(t + 255) / 256, 256, 0, stream>>>(w5, bf5, 512, 256);
  t = (512 / 32) * 16 * 9 * 256;
  k_pack_wfrag<<<(t + 255) / 256, 256, 0, stream>>>(w6, bf6, 512, 512);
  t = 1024 * 256;
  k_pack_fcwT<<<(t + 255) / 256, 256, 0, stream>>>(fw1, pfw1, 1024, 8192);
  t = 1024 * 32;
  k_pack_fcwT<<<(t + 255) / 256, 256, 0, stream>>>(fw2, pfw2, 1024, 1024);
  t = 10 * 32;
  k_pack_fcw<<<(t + 255) / 256, 256, 0, stream>>>(fw3, pfw3, 10, 1024);

  k_conv1<<<16384, 256, 0, stream>>>(x, w1, b1, K[0][0], K[0][1], a1);
  k_bconv11<4><<<dim3(64, 8, 1), 512, 0, stream>>>(a1, bf2, b2, 256,
                                                   K[1][0], K[1][1], a2);
  k_bconv11<8><<<dim3(64, 8, 1), 512, 0, stream>>>(a2, bf3, b3, 256,
                                                   K[2][0], K[2][1], a3);
  k_bconv11<8><<<dim3(64, 8, 1), 512, 0, stream>>>(a3, bf4, b4, 256,
                                                   K[3][0], K[3][1], a4);
  k_bconv11<8><<<dim3(64, 8, 2), 512, 0, stream>>>(a4, bf5, b5, 512,
                                                   K[4][0], K[4][1], a5);
  k_bconv11<16><<<dim3(64, 8, 2), 512, 0, stream>>>(a5, bf6, b6, 512,
                                                    K[5][0], K[5][1], a6);
  k_repack<<<(4096 * 256 + 255) / 256, 256, 0, stream>>>(a6, f0);
  k_fct<256><<<dim3(128, 16), 256, 0, stream>>>(f0, pfw1, fb1, 1024,
                                                K[6][0], K[6][1], f1);
  k_fct<32><<<dim3(128, 16), 256, 0, stream>>>(f1, pfw2, fb2, 1024,
                                               K[7][0], K[7][1], f2);
  k_fc3<<<4096, 64, 0, stream>>>(f2, pfw3, fb3, K[8][0], K[8][1],
                                 (float*)d_out);
}